// Round 5
// baseline (882.286 us; speedup 1.0000x reference)
//
#include <hip/hip_runtime.h>

#define NN 50000
#define MPAD 50176  // 392 * 128
#define DD 512
#define NE 150000

typedef float f32x4 __attribute__((ext_vector_type(4)));
typedef float f32x8 __attribute__((ext_vector_type(8)));
typedef __bf16 bf16x8 __attribute__((ext_vector_type(8)));
typedef unsigned short u16x8 __attribute__((ext_vector_type(8)));

__device__ __forceinline__ void gload16(const void* g, void* l) {
  __builtin_amdgcn_global_load_lds((const __attribute__((address_space(1))) void*)g,
                                   (__attribute__((address_space(3))) void*)l, 16, 0, 0);
}

// 32 MFMAs of one K-step (BK=64) from LDS tiles la (128xBK) / lb (256xBK)
#define MFMA_STEP(la, lb)                                                                       \
  {                                                                                             \
    _Pragma("unroll") for (int kk = 0; kk < 2; ++kk) {                                          \
      bf16x8 av[4], bv[4];                                                                      \
      _Pragma("unroll") for (int i = 0; i < 4; ++i)                                             \
          av[i] = *reinterpret_cast<const bf16x8*>(&(la)[(rg + i * 16 + fr) * 64 + kk * 32 + fg * 8]); \
      _Pragma("unroll") for (int j = 0; j < 4; ++j)                                             \
          bv[j] = *reinterpret_cast<const bf16x8*>(&(lb)[(cg + j * 16 + fr) * 64 + kk * 32 + fg * 8]); \
      _Pragma("unroll") for (int i = 0; i < 4; ++i)                                             \
          _Pragma("unroll") for (int j = 0; j < 4; ++j)                                         \
              acc[i][j] = __builtin_amdgcn_mfma_f32_16x16x32_bf16(av[i], bv[j], acc[i][j], 0, 0, 0); \
    }                                                                                           \
  }

// ============ weight convert: f32 -> bf16 ============
__global__ void wconv_k(const float* __restrict__ W1, const float* __restrict__ W2,
                        unsigned short* __restrict__ o1, unsigned short* __restrict__ o2) {
  const size_t i = ((size_t)blockIdx.x * 256 + threadIdx.x) * 8;
  {
    const f32x4* g = reinterpret_cast<const f32x4*>(W1 + i);
    f32x4 a = g[0], b = g[1];
    f32x8 v;
    v[0]=a[0]; v[1]=a[1]; v[2]=a[2]; v[3]=a[3]; v[4]=b[0]; v[5]=b[1]; v[6]=b[2]; v[7]=b[3];
    *reinterpret_cast<bf16x8*>(o1 + i) = __builtin_convertvector(v, bf16x8);
  }
  {
    const f32x4* g = reinterpret_cast<const f32x4*>(W2 + i);
    f32x4 a = g[0], b = g[1];
    f32x8 v;
    v[0]=a[0]; v[1]=a[1]; v[2]=a[2]; v[3]=a[3]; v[4]=b[0]; v[5]=b[1]; v[6]=b[2]; v[7]=b[3];
    *reinterpret_cast<bf16x8*>(o2 + i) = __builtin_convertvector(v, bf16x8);
  }
}

// ============ CSR build ============
__global__ void count_k(const int* __restrict__ dst, int* __restrict__ cnt) {
  const int e = blockIdx.x * 256 + threadIdx.x;
  if (e < NE) atomicAdd(&cnt[dst[e]], 1);
}

__global__ __launch_bounds__(1024) void scan_k(const int* __restrict__ cnt,
                                               int* __restrict__ rowptr,
                                               int* __restrict__ cursor) {
  __shared__ int wsum[16];
  __shared__ int base_s;
  if (threadIdx.x == 0) base_s = 0;
  __syncthreads();
  const int lane = threadIdx.x & 63;
  const int wid = threadIdx.x >> 6;
  for (int c0 = 0; c0 < NN; c0 += 1024) {
    const int i = c0 + threadIdx.x;
    const int v = (i < NN) ? cnt[i] : 0;
    int incl = v;
#pragma unroll
    for (int d = 1; d < 64; d <<= 1) {
      int t = __shfl_up(incl, d);
      if (lane >= d) incl += t;
    }
    if (lane == 63) wsum[wid] = incl;
    __syncthreads();
    if (wid == 0 && lane < 16) {
      int wv = wsum[lane];
#pragma unroll
      for (int d = 1; d < 16; d <<= 1) {
        int t = __shfl_up(wv, d);
        if (lane >= d) wv += t;
      }
      wsum[lane] = wv;
    }
    __syncthreads();
    const int waveoff = wid ? wsum[wid - 1] : 0;
    const int excl = base_s + waveoff + incl - v;
    if (i < NN) {
      rowptr[i] = excl;
      cursor[i] = excl;
    }
    __syncthreads();
    if (threadIdx.x == 0) base_s += wsum[15];
    __syncthreads();
  }
  if (threadIdx.x == 0) rowptr[NN] = base_s;
}

__global__ void fill_k(const int* __restrict__ src, const int* __restrict__ dst,
                       int* __restrict__ cursor, int* __restrict__ csrc) {
  const int e = blockIdx.x * 256 + threadIdx.x;
  if (e < NE) {
    const int pos = atomicAdd(&cursor[dst[e]], 1);
    csrc[pos] = src[e];
  }
}

// ============ aggregation ============
__global__ __launch_bounds__(256) void agg_f32_k(const float* __restrict__ h,
                                                 const int* __restrict__ rowptr,
                                                 const int* __restrict__ csrc,
                                                 unsigned short* __restrict__ xout) {
  const int node = blockIdx.x * 4 + (threadIdx.x >> 6);
  const int lane = threadIdx.x & 63;
  const f32x4* row = reinterpret_cast<const f32x4*>(h + (size_t)node * DD + lane * 8);
  f32x4 a0 = row[0], a1 = row[1];
  const int p1 = rowptr[node + 1];
  for (int p = rowptr[node]; p < p1; ++p) {
    const int s = csrc[p];
    const f32x4* rs = reinterpret_cast<const f32x4*>(h + (size_t)s * DD + lane * 8);
    a0 += rs[0];
    a1 += rs[1];
  }
  f32x8 vf;
  vf[0]=a0[0]; vf[1]=a0[1]; vf[2]=a0[2]; vf[3]=a0[3];
  vf[4]=a1[0]; vf[5]=a1[1]; vf[6]=a1[2]; vf[7]=a1[3];
  *reinterpret_cast<bf16x8*>(xout + (size_t)node * DD + lane * 8) =
      __builtin_convertvector(vf, bf16x8);
}

__global__ __launch_bounds__(256) void agg_bf16_k(const unsigned short* __restrict__ h,
                                                  const int* __restrict__ rowptr,
                                                  const int* __restrict__ csrc,
                                                  unsigned short* __restrict__ xout) {
  const int node = blockIdx.x * 4 + (threadIdx.x >> 6);
  const int lane = threadIdx.x & 63;
  u16x8 sv = *reinterpret_cast<const u16x8*>(h + (size_t)node * DD + lane * 8);
  f32x8 acc = __builtin_convertvector(__builtin_bit_cast(bf16x8, sv), f32x8);
  const int p1 = rowptr[node + 1];
  for (int p = rowptr[node]; p < p1; ++p) {
    const int s = csrc[p];
    u16x8 rv = *reinterpret_cast<const u16x8*>(h + (size_t)s * DD + lane * 8);
    acc += __builtin_convertvector(__builtin_bit_cast(bf16x8, rv), f32x8);
  }
  *reinterpret_cast<bf16x8*>(xout + (size_t)node * DD + lane * 8) =
      __builtin_convertvector(acc, bf16x8);
}

// ============ GEMM1: Z = bf16( xin @ W1bf^T ), stats += colsum(z), colsum(z^2) ============
// 128x256 tile, 8 waves. 3-deep ring (A 3x16KB, B 3x32KB), counted vmcnt(6), raw s_barrier.
__global__ __launch_bounds__(512, 2) void gemm1_k(
    const unsigned short* __restrict__ A, const unsigned short* __restrict__ B,
    unsigned short* __restrict__ Z, float* __restrict__ stats) {
  // memory order [A0][A2][A1][B0][B2][B1] so epilogue C (64KB at B0) covers B0+B2, not B1
  __shared__ unsigned short sm[73728];  // 144 KB
  constexpr int AOFF[3] = {0, 16384, 8192};
  constexpr int BOFF[3] = {24576, 57344, 40960};
  const int tid = threadIdx.x;
  const int lane = tid & 63;
  const int w = tid >> 6;
  const int rg = (w >> 2) * 64;
  const int cg = (w & 3) * 64;
  const int fr = lane & 15;
  const int fg = lane >> 4;
  const int brow = blockIdx.y * 128;
  const int bcol = blockIdx.x * 256;
  const char* Ab = (const char*)A + (size_t)brow * 1024;
  const char* Bb = (const char*)B + (size_t)bcol * 1024;
  const int srow = tid >> 3;
  const int sc16 = (tid & 7) * 16;
  const int sce = (tid & 7) * 8;

  f32x4 acc[4][4] = {};

  // prologue: stage tiles 0,1 (12 gloads in flight)
#pragma unroll
  for (int t = 0; t < 2; ++t) {
#pragma unroll
    for (int i = 0; i < 2; ++i)
      gload16(Ab + (size_t)(i * 64 + srow) * 1024 + t * 128 + sc16,
              &sm[AOFF[t] + (i * 64 + srow) * 64 + sce]);
#pragma unroll
    for (int i = 0; i < 4; ++i)
      gload16(Bb + (size_t)(i * 64 + srow) * 1024 + t * 128 + sc16,
              &sm[BOFF[t] + (i * 64 + srow) * 64 + sce]);
  }

#pragma unroll
  for (int kt = 0; kt < 8; ++kt) {
    if (kt < 7) asm volatile("s_waitcnt vmcnt(6)" ::: "memory");
    else        asm volatile("s_waitcnt vmcnt(0)" ::: "memory");
    __builtin_amdgcn_s_barrier();
    __builtin_amdgcn_sched_barrier(0);
    if (kt + 2 < 8) {
      const int t2 = kt + 2;
#pragma unroll
      for (int i = 0; i < 2; ++i)
        gload16(Ab + (size_t)(i * 64 + srow) * 1024 + t2 * 128 + sc16,
                &sm[AOFF[t2 % 3] + (i * 64 + srow) * 64 + sce]);
#pragma unroll
      for (int i = 0; i < 4; ++i)
        gload16(Bb + (size_t)(i * 64 + srow) * 1024 + t2 * 128 + sc16,
                &sm[BOFF[t2 % 3] + (i * 64 + srow) * 64 + sce]);
    }
    const unsigned short* la = &sm[AOFF[kt % 3]];
    const unsigned short* lb = &sm[BOFF[kt % 3]];
    MFMA_STEP(la, lb)
  }

  // stats (from acc regs; pad rows contribute 0)
#pragma unroll
  for (int j = 0; j < 4; ++j) {
    const int col = bcol + cg + j * 16 + fr;
    float s1 = 0.f, s2 = 0.f;
#pragma unroll
    for (int i = 0; i < 4; ++i)
#pragma unroll
      for (int r = 0; r < 4; ++r) {
        const float v = acc[i][j][r];
        s1 += v;
        s2 += v * v;
      }
    s1 += __shfl_down(s1, 32);
    s2 += __shfl_down(s2, 32);
    s1 += __shfl_down(s1, 16);
    s2 += __shfl_down(s2, 16);
    if (lane < 16) {
      atomicAdd(&stats[col], s1);
      atomicAdd(&stats[DD + col], s2);
    }
  }

  // LDS-staged C write (coalesced 16B stores)
  unsigned short* C = &sm[24576];
#pragma unroll
  for (int j = 0; j < 4; ++j)
#pragma unroll
    for (int i = 0; i < 4; ++i)
#pragma unroll
      for (int r = 0; r < 4; ++r) {
        __bf16 b = (__bf16)acc[i][j][r];
        C[(rg + i * 16 + fg * 4 + r) * 256 + cg + j * 16 + fr] =
            __builtin_bit_cast(unsigned short, b);
      }
  asm volatile("s_waitcnt lgkmcnt(0)" ::: "memory");
  __builtin_amdgcn_s_barrier();
  const int orow = tid >> 2;
  const int oseg = (tid & 3) * 64;
  const unsigned short* cr = &C[orow * 256 + oseg];
  unsigned short* zg = Z + (size_t)(brow + orow) * DD + bcol + oseg;
#pragma unroll
  for (int i = 0; i < 8; ++i) {
    const int i2 = ((i + tid) & 7) * 8;  // stagger to spread LDS banks
    *reinterpret_cast<u16x8*>(zg + i2) = *reinterpret_cast<const u16x8*>(cr + i2);
  }
}

// ============ BN finalize ============
__global__ void bnfin_k(const float* __restrict__ stats, const float* __restrict__ gamma,
                        const float* __restrict__ beta, float* __restrict__ scsh) {
  const int n = threadIdx.x;
  const float inv = 1.0f / (float)NN;
  const float mu = stats[n] * inv;
  const float var = stats[DD + n] * inv - mu * mu;
  const float sc = rsqrtf(var + 1e-5f) * gamma[n];
  scsh[n] = sc;
  scsh[DD + n] = beta[n] - mu * sc;
}

// BN+ReLU transform of two z-rows -> bf16 -> ds_write into A buffer
__device__ __forceinline__ void bn_stage(u16x8 z0v, u16x8 z1v, bool v0, bool v1,
                                         const float* sc_base, int c0,
                                         unsigned short* adst, int srow, int sce) {
  f32x4 sca = *reinterpret_cast<const f32x4*>(sc_base + c0);
  f32x4 scb = *reinterpret_cast<const f32x4*>(sc_base + c0 + 4);
  f32x4 sha = *reinterpret_cast<const f32x4*>(sc_base + 512 + c0);
  f32x4 shb = *reinterpret_cast<const f32x4*>(sc_base + 512 + c0 + 4);
  f32x8 f0 = __builtin_convertvector(__builtin_bit_cast(bf16x8, z0v), f32x8);
  f32x8 f1 = __builtin_convertvector(__builtin_bit_cast(bf16x8, z1v), f32x8);
  f32x8 a0 = {}, a1 = {};
  if (v0) {
#pragma unroll
    for (int q = 0; q < 4; ++q) {
      a0[q]     = fmaxf(f0[q]     * sca[q] + sha[q], 0.f);
      a0[q + 4] = fmaxf(f0[q + 4] * scb[q] + shb[q], 0.f);
    }
  }
  if (v1) {
#pragma unroll
    for (int q = 0; q < 4; ++q) {
      a1[q]     = fmaxf(f1[q]     * sca[q] + sha[q], 0.f);
      a1[q + 4] = fmaxf(f1[q + 4] * scb[q] + shb[q], 0.f);
    }
  }
  *reinterpret_cast<bf16x8*>(adst + srow * 64 + sce) = __builtin_convertvector(a0, bf16x8);
  *reinterpret_cast<bf16x8*>(adst + (srow + 64) * 64 + sce) = __builtin_convertvector(a1, bf16x8);
}

// ============ GEMM2: H = bf16(relu(z*sc+sh) @ W2bf^T + b2), fused colsum ============
// A reg-staged (BN+ReLU fused, dist-2 z prefetch, 2-buf), B gload_lds 3-ring, vmcnt(4).
__global__ __launch_bounds__(512, 2) void gemm2_k(
    const unsigned short* __restrict__ Zin, const unsigned short* __restrict__ B,
    const float* __restrict__ scshG, const float* __restrict__ b2,
    unsigned short* __restrict__ H, float* __restrict__ colsum,
    const int write_h, const int do_colsum) {
  __shared__ char smc[135168];  // 128KB rings + C-overlay + 4KB scsh
  unsigned short* sm = (unsigned short*)smc;
  float* lsc = (float*)(smc + 131072);
  constexpr int AOFF[2] = {0, 8192};
  constexpr int BOFF[3] = {16384, 49152, 32768};  // order [B0][B2][B1]
  const int tid = threadIdx.x;
  const int lane = tid & 63;
  const int w = tid >> 6;
  const int rg = (w >> 2) * 64;
  const int cg = (w & 3) * 64;
  const int fr = lane & 15;
  const int fg = lane >> 4;
  const int brow = blockIdx.y * 128;
  const int bcol = blockIdx.x * 256;
  const char* Bb = (const char*)B + (size_t)bcol * 1024;
  const int srow = tid >> 3;
  const int sc16 = (tid & 7) * 16;
  const int sce = (tid & 7) * 8;
  const int r0 = brow + srow;
  const int r1 = r0 + 64;
  const bool v0 = r0 < NN;
  const bool v1 = r1 < NN;
  const unsigned short* zrow0 = Zin + (size_t)r0 * DD + sce;
  const unsigned short* zrow1 = Zin + (size_t)r1 * DD + sce;

  f32x4 acc[4][4] = {};
  u16x8 zE0, zE1, zO0, zO1;  // even/odd tile z registers

  // ---- prologue ----
  zE0 = *reinterpret_cast<const u16x8*>(zrow0);       // z tile 0
  zE1 = *reinterpret_cast<const u16x8*>(zrow1);
  lsc[tid * 2] = scshG[tid * 2];                      // scsh -> LDS
  lsc[tid * 2 + 1] = scshG[tid * 2 + 1];
  // transform tile 0 straight from global scsh (drains all vm before B issue)
  bn_stage(zE0, zE1, v0, v1, scshG, sce, &sm[AOFF[0]], srow, sce);
#pragma unroll
  for (int i = 0; i < 4; ++i)                         // B(0)
    gload16(Bb + (size_t)(i * 64 + srow) * 1024 + 0 * 128 + sc16,
            &sm[BOFF[0] + (i * 64 + srow) * 64 + sce]);
  zO0 = *reinterpret_cast<const u16x8*>(zrow0 + 64);  // z tile 1
  zO1 = *reinterpret_cast<const u16x8*>(zrow1 + 64);
#pragma unroll
  for (int i = 0; i < 4; ++i)                         // B(1)
    gload16(Bb + (size_t)(i * 64 + srow) * 1024 + 1 * 128 + sc16,
            &sm[BOFF[1] + (i * 64 + srow) * 64 + sce]);
  asm volatile("s_waitcnt lgkmcnt(0)" ::: "memory");  // scsh + A0 ds_writes visible

  // FIFO entering loop: [B0:4, z1:2, B1:4]
#pragma unroll
  for (int kt = 0; kt < 8; ++kt) {
    if (kt < 7) asm volatile("s_waitcnt vmcnt(4)" ::: "memory");
    else        asm volatile("s_waitcnt vmcnt(0)" ::: "memory");
    __builtin_amdgcn_s_barrier();
    __builtin_amdgcn_sched_barrier(0);
    if (kt + 1 < 8) {  // transform+stage A(kt+1) from regs (scsh via LDS)
      if ((kt & 1) == 0)
        bn_stage(zO0, zO1, v0, v1, lsc, (kt + 1) * 64 + sce, &sm[AOFF[(kt + 1) & 1]], srow, sce);
      else
        bn_stage(zE0, zE1, v0, v1, lsc, (kt + 1) * 64 + sce, &sm[AOFF[(kt + 1) & 1]], srow, sce);
    }
    if (kt + 2 < 8) {  // issue z(kt+2) regs then B(kt+2) gloads
      const int t2 = kt + 2;
      if ((kt & 1) == 0) {
        zE0 = *reinterpret_cast<const u16x8*>(zrow0 + t2 * 64);
        zE1 = *reinterpret_cast<const u16x8*>(zrow1 + t2 * 64);
      } else {
        zO0 = *reinterpret_cast<const u16x8*>(zrow0 + t2 * 64);
        zO1 = *reinterpret_cast<const u16x8*>(zrow1 + t2 * 64);
      }
#pragma unroll
      for (int i = 0; i < 4; ++i)
        gload16(Bb + (size_t)(i * 64 + srow) * 1024 + t2 * 128 + sc16,
                &sm[BOFF[t2 % 3] + (i * 64 + srow) * 64 + sce]);
    }
    const unsigned short* la = &sm[AOFF[kt & 1]];
    const unsigned short* lb = &sm[BOFF[kt % 3]];
    MFMA_STEP(la, lb)
  }

  // colsum (pre-bias, from acc; pad rows contribute 0)
  if (do_colsum) {
#pragma unroll
    for (int j = 0; j < 4; ++j) {
      const int col = bcol + cg + j * 16 + fr;
      float s1 = 0.f;
#pragma unroll
      for (int i = 0; i < 4; ++i)
#pragma unroll
        for (int r = 0; r < 4; ++r) s1 += acc[i][j][r];
      s1 += __shfl_down(s1, 32);
      s1 += __shfl_down(s1, 16);
      if (lane < 16) atomicAdd(&colsum[col], s1);
    }
  }

  if (write_h) {  // LDS-staged H write (+b2), coalesced
    unsigned short* C = &sm[16384];
#pragma unroll
    for (int j = 0; j < 4; ++j) {
      const float bb = b2[bcol + cg + j * 16 + fr];
#pragma unroll
      for (int i = 0; i < 4; ++i)
#pragma unroll
        for (int r = 0; r < 4; ++r) {
          __bf16 b = (__bf16)(acc[i][j][r] + bb);
          C[(rg + i * 16 + fg * 4 + r) * 256 + cg + j * 16 + fr] =
              __builtin_bit_cast(unsigned short, b);
        }
    }
    asm volatile("s_waitcnt lgkmcnt(0)" ::: "memory");
    __builtin_amdgcn_s_barrier();
    const int orow = tid >> 2;
    const int oseg = (tid & 3) * 64;
    const unsigned short* cr = &C[orow * 256 + oseg];
    unsigned short* hg = H + (size_t)(brow + orow) * DD + bcol + oseg;
#pragma unroll
    for (int i = 0; i < 8; ++i) {
      const int i2 = ((i + tid) & 7) * 8;
      *reinterpret_cast<u16x8*>(hg + i2) = *reinterpret_cast<const u16x8*>(cr + i2);
    }
  }
}

// ============ final outputs ============
__global__ void out_k(const float* __restrict__ colsum, const float* __restrict__ b2_all,
                      float* __restrict__ out) {
  const int n = threadIdx.x;
  const float inv = 1.0f / (float)NN;
  out[n]      = colsum[DD + n] * inv + b2_all[3 * DD + n];  // outs[-1] = layer 3
  out[DD + n] = colsum[n] * inv      + b2_all[2 * DD + n];  // outs[-2] = layer 2
}

extern "C" void kernel_launch(void* const* d_in, const int* in_sizes, int n_in,
                              void* d_out, int out_size, void* d_ws, size_t ws_size,
                              hipStream_t stream) {
  const float* x     = (const float*)d_in[0];
  const float* W1    = (const float*)d_in[1];
  // d_in[2] = b1: cancels exactly in training-mode BatchNorm -> unused
  const float* gamma = (const float*)d_in[3];
  const float* beta  = (const float*)d_in[4];
  const float* W2    = (const float*)d_in[5];
  const float* b2    = (const float*)d_in[6];
  const int*   src   = (const int*)d_in[7];
  const int*   dst   = (const int*)d_in[8];
  float* out = (float*)d_out;

  char* ws = (char*)d_ws;
  const size_t ABYTES = (size_t)MPAD * DD * 2;  // 51,380,224
  unsigned short* xin    = (unsigned short*)(ws);
  unsigned short* z      = (unsigned short*)(ws + ABYTES);
  unsigned short* h      = (unsigned short*)(ws + 2 * ABYTES);
  unsigned short* wb1    = (unsigned short*)(ws + 3 * ABYTES);
  unsigned short* wb2    = (unsigned short*)(ws + 3 * ABYTES + 2097152);
  int*            rowptr = (int*)(ws + 3 * ABYTES + 4194304);
  int*            cursor = (int*)(ws + 3 * ABYTES + 4494304);
  int*            csrc   = (int*)(ws + 3 * ABYTES + 4694304);
  float*          stats  = (float*)(ws + 3 * ABYTES + 5394304);
  float*          colsum = (float*)(ws + 3 * ABYTES + 5398400);
  float*          scsh   = (float*)(ws + 3 * ABYTES + 5402496);

  // weights -> bf16 (once)
  wconv_k<<<512, 256, 0, stream>>>(W1, W2, wb1, wb2);
  // zero xin pad rows once (agg never writes them; zeros keep stats/colsum exact)
  hipMemsetAsync(xin + (size_t)NN * DD, 0, (size_t)(MPAD - NN) * DD * 2, stream);

  // CSR build (once)
  hipMemsetAsync(cursor, 0, NN * sizeof(int), stream);
  count_k<<<(NE + 255) / 256, 256, 0, stream>>>(dst, cursor);
  scan_k<<<1, 1024, 0, stream>>>(cursor, rowptr, cursor);
  fill_k<<<(NE + 255) / 256, 256, 0, stream>>>(src, dst, cursor, csrc);

  hipMemsetAsync(colsum, 0, 2 * DD * sizeof(float), stream);

  dim3 gg(DD / 256, MPAD / 128);  // (2, 392)
  for (int l = 0; l < 4; ++l) {
    if (l == 0)
      agg_f32_k<<<NN / 4, 256, 0, stream>>>(x, rowptr, csrc, xin);
    else
      agg_bf16_k<<<NN / 4, 256, 0, stream>>>(h, rowptr, csrc, xin);
    hipMemsetAsync(stats, 0, 2 * DD * sizeof(float), stream);
    gemm1_k<<<gg, 512, 0, stream>>>(xin, wb1 + (size_t)l * DD * DD, z, stats);
    bnfin_k<<<1, DD, 0, stream>>>(stats, gamma + l * DD, beta + l * DD, scsh);
    const int slot = (l == 2) ? 0 : ((l == 3) ? 1 : -1);
    gemm2_k<<<gg, 512, 0, stream>>>(z, wb2 + (size_t)l * DD * DD, scsh, b2 + l * DD,
                                    h, colsum + (slot == 1 ? DD : 0),
                                    (l < 3) ? 1 : 0, (slot >= 0) ? 1 : 0);
  }
  out_k<<<1, DD, 0, stream>>>(colsum, b2, out);
}

// Round 6
// 835.942 us; speedup vs baseline: 1.0554x; 1.0554x over previous
//
#include <hip/hip_runtime.h>

#define NN 50000
#define MPAD 50176  // 392 * 128
#define DD 512
#define NE 150000

typedef float f32x4 __attribute__((ext_vector_type(4)));
typedef float f32x8 __attribute__((ext_vector_type(8)));
typedef __bf16 bf16x8 __attribute__((ext_vector_type(8)));
typedef unsigned short u16x8 __attribute__((ext_vector_type(8)));

__device__ __forceinline__ void gload16(const void* g, void* l) {
  __builtin_amdgcn_global_load_lds((const __attribute__((address_space(1))) void*)g,
                                   (__attribute__((address_space(3))) void*)l, 16, 0, 0);
}

// 32 MFMAs of one K-step (BK=64) from LDS tiles la (128xBK) / lb (256xBK).
// Fragment reads use the T2 swizzle: phys_slot = (kk*4+fg) ^ (row&7), row&7 == fr&7 == sx.
#define MFMA_STEP(la, lb)                                                                       \
  {                                                                                             \
    _Pragma("unroll") for (int kk = 0; kk < 2; ++kk) {                                          \
      bf16x8 av[4], bv[4];                                                                      \
      const int so = ((kk * 4 + fg) ^ sx) * 8;                                                  \
      _Pragma("unroll") for (int i = 0; i < 4; ++i)                                             \
          av[i] = *reinterpret_cast<const bf16x8*>(&(la)[(rg + i * 16 + fr) * 64 + so]);        \
      _Pragma("unroll") for (int j = 0; j < 4; ++j)                                             \
          bv[j] = *reinterpret_cast<const bf16x8*>(&(lb)[(cg + j * 16 + fr) * 64 + so]);        \
      _Pragma("unroll") for (int i = 0; i < 4; ++i)                                             \
          _Pragma("unroll") for (int j = 0; j < 4; ++j)                                         \
              acc[i][j] = __builtin_amdgcn_mfma_f32_16x16x32_bf16(av[i], bv[j], acc[i][j], 0, 0, 0); \
    }                                                                                           \
  }

// ============ weight convert: f32 -> bf16 ============
__global__ void wconv_k(const float* __restrict__ W1, const float* __restrict__ W2,
                        unsigned short* __restrict__ o1, unsigned short* __restrict__ o2) {
  const size_t i = ((size_t)blockIdx.x * 256 + threadIdx.x) * 8;
  {
    const f32x4* g = reinterpret_cast<const f32x4*>(W1 + i);
    f32x4 a = g[0], b = g[1];
    f32x8 v;
    v[0]=a[0]; v[1]=a[1]; v[2]=a[2]; v[3]=a[3]; v[4]=b[0]; v[5]=b[1]; v[6]=b[2]; v[7]=b[3];
    *reinterpret_cast<bf16x8*>(o1 + i) = __builtin_convertvector(v, bf16x8);
  }
  {
    const f32x4* g = reinterpret_cast<const f32x4*>(W2 + i);
    f32x4 a = g[0], b = g[1];
    f32x8 v;
    v[0]=a[0]; v[1]=a[1]; v[2]=a[2]; v[3]=a[3]; v[4]=b[0]; v[5]=b[1]; v[6]=b[2]; v[7]=b[3];
    *reinterpret_cast<bf16x8*>(o2 + i) = __builtin_convertvector(v, bf16x8);
  }
}

// ============ CSR build ============
__global__ void count_k(const int* __restrict__ dst, int* __restrict__ cnt) {
  const int e = blockIdx.x * 256 + threadIdx.x;
  if (e < NE) atomicAdd(&cnt[dst[e]], 1);
}

__global__ __launch_bounds__(1024) void scan_k(const int* __restrict__ cnt,
                                               int* __restrict__ rowptr,
                                               int* __restrict__ cursor) {
  __shared__ int wsum[16];
  __shared__ int base_s;
  if (threadIdx.x == 0) base_s = 0;
  __syncthreads();
  const int lane = threadIdx.x & 63;
  const int wid = threadIdx.x >> 6;
  for (int c0 = 0; c0 < NN; c0 += 1024) {
    const int i = c0 + threadIdx.x;
    const int v = (i < NN) ? cnt[i] : 0;
    int incl = v;
#pragma unroll
    for (int d = 1; d < 64; d <<= 1) {
      int t = __shfl_up(incl, d);
      if (lane >= d) incl += t;
    }
    if (lane == 63) wsum[wid] = incl;
    __syncthreads();
    if (wid == 0 && lane < 16) {
      int wv = wsum[lane];
#pragma unroll
      for (int d = 1; d < 16; d <<= 1) {
        int t = __shfl_up(wv, d);
        if (lane >= d) wv += t;
      }
      wsum[lane] = wv;
    }
    __syncthreads();
    const int waveoff = wid ? wsum[wid - 1] : 0;
    const int excl = base_s + waveoff + incl - v;
    if (i < NN) {
      rowptr[i] = excl;
      cursor[i] = excl;
    }
    __syncthreads();
    if (threadIdx.x == 0) base_s += wsum[15];
    __syncthreads();
  }
  if (threadIdx.x == 0) rowptr[NN] = base_s;
}

__global__ void fill_k(const int* __restrict__ src, const int* __restrict__ dst,
                       int* __restrict__ cursor, int* __restrict__ csrc) {
  const int e = blockIdx.x * 256 + threadIdx.x;
  if (e < NE) {
    const int pos = atomicAdd(&cursor[dst[e]], 1);
    csrc[pos] = src[e];
  }
}

// ============ aggregation ============
__global__ __launch_bounds__(256) void agg_f32_k(const float* __restrict__ h,
                                                 const int* __restrict__ rowptr,
                                                 const int* __restrict__ csrc,
                                                 unsigned short* __restrict__ xout) {
  const int node = blockIdx.x * 4 + (threadIdx.x >> 6);
  const int lane = threadIdx.x & 63;
  const f32x4* row = reinterpret_cast<const f32x4*>(h + (size_t)node * DD + lane * 8);
  f32x4 a0 = row[0], a1 = row[1];
  const int p1 = rowptr[node + 1];
  for (int p = rowptr[node]; p < p1; ++p) {
    const int s = csrc[p];
    const f32x4* rs = reinterpret_cast<const f32x4*>(h + (size_t)s * DD + lane * 8);
    a0 += rs[0];
    a1 += rs[1];
  }
  f32x8 vf;
  vf[0]=a0[0]; vf[1]=a0[1]; vf[2]=a0[2]; vf[3]=a0[3];
  vf[4]=a1[0]; vf[5]=a1[1]; vf[6]=a1[2]; vf[7]=a1[3];
  *reinterpret_cast<bf16x8*>(xout + (size_t)node * DD + lane * 8) =
      __builtin_convertvector(vf, bf16x8);
}

__global__ __launch_bounds__(256) void agg_bf16_k(const unsigned short* __restrict__ h,
                                                  const int* __restrict__ rowptr,
                                                  const int* __restrict__ csrc,
                                                  unsigned short* __restrict__ xout) {
  const int node = blockIdx.x * 4 + (threadIdx.x >> 6);
  const int lane = threadIdx.x & 63;
  u16x8 sv = *reinterpret_cast<const u16x8*>(h + (size_t)node * DD + lane * 8);
  f32x8 acc = __builtin_convertvector(__builtin_bit_cast(bf16x8, sv), f32x8);
  const int p1 = rowptr[node + 1];
  for (int p = rowptr[node]; p < p1; ++p) {
    const int s = csrc[p];
    u16x8 rv = *reinterpret_cast<const u16x8*>(h + (size_t)s * DD + lane * 8);
    acc += __builtin_convertvector(__builtin_bit_cast(bf16x8, rv), f32x8);
  }
  *reinterpret_cast<bf16x8*>(xout + (size_t)node * DD + lane * 8) =
      __builtin_convertvector(acc, bf16x8);
}

// ============ GEMM1: Z = bf16( xin @ W1bf^T ), stats += colsum(z), colsum(z^2) ============
// 128x256 tile, 8 waves, 3-ring, counted vmcnt(6), raw s_barrier, T2-swizzled LDS.
__global__ __launch_bounds__(512, 2) void gemm1_k(
    const unsigned short* __restrict__ A, const unsigned short* __restrict__ B,
    unsigned short* __restrict__ Z, float* __restrict__ stats) {
  // memory order [A0][A2][A1][B0][B2][B1]; epilogue C (64KB) covers B0+B2 (kt=7 uses A1,B1)
  __shared__ unsigned short sm[73728];  // 144 KB
  constexpr int AOFF[3] = {0, 16384, 8192};
  constexpr int BOFF[3] = {24576, 57344, 40960};
  const int tid = threadIdx.x;
  const int lane = tid & 63;
  const int w = tid >> 6;
  const int rg = (w >> 2) * 64;
  const int cg = (w & 3) * 64;
  const int fr = lane & 15;
  const int fg = lane >> 4;
  const int sx = fr & 7;               // fragment-read swizzle key (= row&7)
  const int brow = blockIdx.y * 128;
  const int bcol = blockIdx.x * 256;
  const char* Ab = (const char*)A + (size_t)brow * 1024;
  const char* Bb = (const char*)B + (size_t)bcol * 1024;
  const int srow = tid >> 3;
  const int sce = (tid & 7) * 8;                        // linear LDS dest (elem)
  const int sswz = (((tid & 7) ^ (srow & 7))) * 16;     // pre-swizzled global slot (bytes)

  f32x4 acc[4][4] = {};

  // prologue: stage tiles 0,1 (12 gloads in flight)
#pragma unroll
  for (int t = 0; t < 2; ++t) {
#pragma unroll
    for (int i = 0; i < 2; ++i)
      gload16(Ab + (size_t)(i * 64 + srow) * 1024 + t * 128 + sswz,
              &sm[AOFF[t] + (i * 64 + srow) * 64 + sce]);
#pragma unroll
    for (int i = 0; i < 4; ++i)
      gload16(Bb + (size_t)(i * 64 + srow) * 1024 + t * 128 + sswz,
              &sm[BOFF[t] + (i * 64 + srow) * 64 + sce]);
  }

#pragma unroll
  for (int kt = 0; kt < 8; ++kt) {
    if (kt < 7) asm volatile("s_waitcnt vmcnt(6)" ::: "memory");
    else        asm volatile("s_waitcnt vmcnt(0)" ::: "memory");
    __builtin_amdgcn_s_barrier();
    __builtin_amdgcn_sched_barrier(0);
    if (kt + 2 < 8) {
      const int t2 = kt + 2;
#pragma unroll
      for (int i = 0; i < 2; ++i)
        gload16(Ab + (size_t)(i * 64 + srow) * 1024 + t2 * 128 + sswz,
                &sm[AOFF[t2 % 3] + (i * 64 + srow) * 64 + sce]);
#pragma unroll
      for (int i = 0; i < 4; ++i)
        gload16(Bb + (size_t)(i * 64 + srow) * 1024 + t2 * 128 + sswz,
                &sm[BOFF[t2 % 3] + (i * 64 + srow) * 64 + sce]);
    }
    const unsigned short* la = &sm[AOFF[kt % 3]];
    const unsigned short* lb = &sm[BOFF[kt % 3]];
    MFMA_STEP(la, lb)
  }

  // stats (from acc regs; pad rows contribute 0)
#pragma unroll
  for (int j = 0; j < 4; ++j) {
    const int col = bcol + cg + j * 16 + fr;
    float s1 = 0.f, s2 = 0.f;
#pragma unroll
    for (int i = 0; i < 4; ++i)
#pragma unroll
      for (int r = 0; r < 4; ++r) {
        const float v = acc[i][j][r];
        s1 += v;
        s2 += v * v;
      }
    s1 += __shfl_down(s1, 32);
    s2 += __shfl_down(s2, 32);
    s1 += __shfl_down(s1, 16);
    s2 += __shfl_down(s2, 16);
    if (lane < 16) {
      atomicAdd(&stats[col], s1);
      atomicAdd(&stats[DD + col], s2);
    }
  }

  // LDS-staged C write (swizzled: phys 16B-slot = logical ^ (row&7))
  unsigned short* C = &sm[24576];
#pragma unroll
  for (int j = 0; j < 4; ++j)
#pragma unroll
    for (int i = 0; i < 4; ++i)
#pragma unroll
      for (int r = 0; r < 4; ++r) {
        const int row = rg + i * 16 + fg * 4 + r;
        const int col = cg + j * 16 + fr;
        __bf16 b = (__bf16)acc[i][j][r];
        C[row * 256 + (((col >> 3) ^ (row & 7)) << 3) + (col & 7)] =
            __builtin_bit_cast(unsigned short, b);
      }
  asm volatile("s_waitcnt lgkmcnt(0)" ::: "memory");
  __builtin_amdgcn_s_barrier();
  const int orow = tid >> 2;
  const int ox = orow & 7;
  const unsigned short* cr = &C[orow * 256];
  unsigned short* zg = Z + (size_t)(brow + orow) * DD + bcol;
#pragma unroll
  for (int i = 0; i < 8; ++i) {
    const int s = (tid & 3) * 8 + ((i + tid) & 7);  // logical 16B slot 0..31
    *reinterpret_cast<u16x8*>(zg + s * 8) = *reinterpret_cast<const u16x8*>(cr + (s ^ ox) * 8);
  }
}

// ============ BN finalize (+ re-zero stats for next layer) ============
__global__ void bnfin_k(float* __restrict__ stats, const float* __restrict__ gamma,
                        const float* __restrict__ beta, float* __restrict__ scsh) {
  const int n = threadIdx.x;
  const float inv = 1.0f / (float)NN;
  const float mu = stats[n] * inv;
  const float var = stats[DD + n] * inv - mu * mu;
  const float sc = rsqrtf(var + 1e-5f) * gamma[n];
  scsh[n] = sc;
  scsh[DD + n] = beta[n] - mu * sc;
  stats[n] = 0.f;
  stats[DD + n] = 0.f;
}

// BN+ReLU transform of two z-rows -> bf16 -> ds_write into A buffer (swizzled offset woff)
__device__ __forceinline__ void bn_stage(u16x8 z0v, u16x8 z1v, bool v0, bool v1,
                                         const float* sc_base, int c0,
                                         unsigned short* adst, int srow, int woff) {
  f32x4 sca = *reinterpret_cast<const f32x4*>(sc_base + c0);
  f32x4 scb = *reinterpret_cast<const f32x4*>(sc_base + c0 + 4);
  f32x4 sha = *reinterpret_cast<const f32x4*>(sc_base + 512 + c0);
  f32x4 shb = *reinterpret_cast<const f32x4*>(sc_base + 512 + c0 + 4);
  f32x8 f0 = __builtin_convertvector(__builtin_bit_cast(bf16x8, z0v), f32x8);
  f32x8 f1 = __builtin_convertvector(__builtin_bit_cast(bf16x8, z1v), f32x8);
  f32x8 a0 = {}, a1 = {};
  if (v0) {
#pragma unroll
    for (int q = 0; q < 4; ++q) {
      a0[q]     = fmaxf(f0[q]     * sca[q] + sha[q], 0.f);
      a0[q + 4] = fmaxf(f0[q + 4] * scb[q] + shb[q], 0.f);
    }
  }
  if (v1) {
#pragma unroll
    for (int q = 0; q < 4; ++q) {
      a1[q]     = fmaxf(f1[q]     * sca[q] + sha[q], 0.f);
      a1[q + 4] = fmaxf(f1[q + 4] * scb[q] + shb[q], 0.f);
    }
  }
  *reinterpret_cast<bf16x8*>(adst + srow * 64 + woff) = __builtin_convertvector(a0, bf16x8);
  *reinterpret_cast<bf16x8*>(adst + (srow + 64) * 64 + woff) = __builtin_convertvector(a1, bf16x8);
}

// ============ GEMM2: H = bf16(relu(z*sc+sh) @ W2bf^T + b2), fused colsum ============
// A reg-staged (BN+ReLU fused, dist-2 z prefetch, 2-buf, swizzled ds_write),
// B gload_lds 3-ring pre-swizzled, counted vmcnt(4).
__global__ __launch_bounds__(512, 2) void gemm2_k(
    const unsigned short* __restrict__ Zin, const unsigned short* __restrict__ B,
    const float* __restrict__ scshG, const float* __restrict__ b2,
    unsigned short* __restrict__ H, float* __restrict__ colsum,
    const int write_h, const int do_colsum) {
  __shared__ char smc[135168];  // 128KB rings + C-overlay + 4KB scsh
  unsigned short* sm = (unsigned short*)smc;
  float* lsc = (float*)(smc + 131072);
  constexpr int AOFF[2] = {0, 8192};
  constexpr int BOFF[3] = {16384, 49152, 32768};  // order [B0][B2][B1]
  const int tid = threadIdx.x;
  const int lane = tid & 63;
  const int w = tid >> 6;
  const int rg = (w >> 2) * 64;
  const int cg = (w & 3) * 64;
  const int fr = lane & 15;
  const int fg = lane >> 4;
  const int sx = fr & 7;
  const int brow = blockIdx.y * 128;
  const int bcol = blockIdx.x * 256;
  const char* Bb = (const char*)B + (size_t)bcol * 1024;
  const int srow = tid >> 3;
  const int sce = (tid & 7) * 8;
  const int sswz = (((tid & 7) ^ (srow & 7))) * 16;  // global pre-swizzle (bytes)
  const int wsz  = (((tid & 7) ^ (srow & 7))) * 8;   // swizzled ds_write offset (elems)
  const int r0 = brow + srow;
  const int r1 = r0 + 64;
  const bool v0 = r0 < NN;
  const bool v1 = r1 < NN;
  const unsigned short* zrow0 = Zin + (size_t)r0 * DD + sce;
  const unsigned short* zrow1 = Zin + (size_t)r1 * DD + sce;

  f32x4 acc[4][4] = {};
  u16x8 zE0, zE1, zO0, zO1;

  // ---- prologue ----
  zE0 = *reinterpret_cast<const u16x8*>(zrow0);       // z tile 0
  zE1 = *reinterpret_cast<const u16x8*>(zrow1);
  lsc[tid * 2] = scshG[tid * 2];                      // scsh -> LDS
  lsc[tid * 2 + 1] = scshG[tid * 2 + 1];
  bn_stage(zE0, zE1, v0, v1, scshG, sce, &sm[AOFF[0]], srow, wsz);
#pragma unroll
  for (int i = 0; i < 4; ++i)                         // B(0)
    gload16(Bb + (size_t)(i * 64 + srow) * 1024 + 0 * 128 + sswz,
            &sm[BOFF[0] + (i * 64 + srow) * 64 + sce]);
  zO0 = *reinterpret_cast<const u16x8*>(zrow0 + 64);  // z tile 1
  zO1 = *reinterpret_cast<const u16x8*>(zrow1 + 64);
#pragma unroll
  for (int i = 0; i < 4; ++i)                         // B(1)
    gload16(Bb + (size_t)(i * 64 + srow) * 1024 + 1 * 128 + sswz,
            &sm[BOFF[1] + (i * 64 + srow) * 64 + sce]);
  asm volatile("s_waitcnt lgkmcnt(0)" ::: "memory");  // scsh + A0 ds_writes visible

  // FIFO entering loop: [B0:4, z1:2, B1:4]
#pragma unroll
  for (int kt = 0; kt < 8; ++kt) {
    if (kt < 7) asm volatile("s_waitcnt vmcnt(4)" ::: "memory");
    else        asm volatile("s_waitcnt vmcnt(0)" ::: "memory");
    __builtin_amdgcn_s_barrier();
    __builtin_amdgcn_sched_barrier(0);
    if (kt + 1 < 8) {
      if ((kt & 1) == 0)
        bn_stage(zO0, zO1, v0, v1, lsc, (kt + 1) * 64 + sce, &sm[AOFF[(kt + 1) & 1]], srow, wsz);
      else
        bn_stage(zE0, zE1, v0, v1, lsc, (kt + 1) * 64 + sce, &sm[AOFF[(kt + 1) & 1]], srow, wsz);
    }
    if (kt + 2 < 8) {
      const int t2 = kt + 2;
      if ((kt & 1) == 0) {
        zE0 = *reinterpret_cast<const u16x8*>(zrow0 + t2 * 64);
        zE1 = *reinterpret_cast<const u16x8*>(zrow1 + t2 * 64);
      } else {
        zO0 = *reinterpret_cast<const u16x8*>(zrow0 + t2 * 64);
        zO1 = *reinterpret_cast<const u16x8*>(zrow1 + t2 * 64);
      }
#pragma unroll
      for (int i = 0; i < 4; ++i)
        gload16(Bb + (size_t)(i * 64 + srow) * 1024 + t2 * 128 + sswz,
                &sm[BOFF[t2 % 3] + (i * 64 + srow) * 64 + sce]);
    }
    const unsigned short* la = &sm[AOFF[kt & 1]];
    const unsigned short* lb = &sm[BOFF[kt % 3]];
    MFMA_STEP(la, lb)
  }

  // colsum (pre-bias, from acc; pad rows contribute 0)
  if (do_colsum) {
#pragma unroll
    for (int j = 0; j < 4; ++j) {
      const int col = bcol + cg + j * 16 + fr;
      float s1 = 0.f;
#pragma unroll
      for (int i = 0; i < 4; ++i)
#pragma unroll
        for (int r = 0; r < 4; ++r) s1 += acc[i][j][r];
      s1 += __shfl_down(s1, 32);
      s1 += __shfl_down(s1, 16);
      if (lane < 16) atomicAdd(&colsum[col], s1);
    }
  }

  if (write_h) {  // LDS-staged H write (+b2), swizzled, coalesced
    unsigned short* C = &sm[16384];
#pragma unroll
    for (int j = 0; j < 4; ++j) {
      const float bb = b2[bcol + cg + j * 16 + fr];
#pragma unroll
      for (int i = 0; i < 4; ++i)
#pragma unroll
        for (int r = 0; r < 4; ++r) {
          const int row = rg + i * 16 + fg * 4 + r;
          const int col = cg + j * 16 + fr;
          __bf16 b = (__bf16)(acc[i][j][r] + bb);
          C[row * 256 + (((col >> 3) ^ (row & 7)) << 3) + (col & 7)] =
              __builtin_bit_cast(unsigned short, b);
        }
    }
    asm volatile("s_waitcnt lgkmcnt(0)" ::: "memory");
    __builtin_amdgcn_s_barrier();
    const int orow = tid >> 2;
    const int ox = orow & 7;
    const unsigned short* cr = &C[orow * 256];
    unsigned short* hg = H + (size_t)(brow + orow) * DD + bcol;
#pragma unroll
    for (int i = 0; i < 8; ++i) {
      const int s = (tid & 3) * 8 + ((i + tid) & 7);
      *reinterpret_cast<u16x8*>(hg + s * 8) = *reinterpret_cast<const u16x8*>(cr + (s ^ ox) * 8);
    }
  }
}

// ============ final outputs ============
__global__ void out_k(const float* __restrict__ colsum, const float* __restrict__ b2_all,
                      float* __restrict__ out) {
  const int n = threadIdx.x;
  const float inv = 1.0f / (float)NN;
  out[n]      = colsum[DD + n] * inv + b2_all[3 * DD + n];  // outs[-1] = layer 3
  out[DD + n] = colsum[n] * inv      + b2_all[2 * DD + n];  // outs[-2] = layer 2
}

extern "C" void kernel_launch(void* const* d_in, const int* in_sizes, int n_in,
                              void* d_out, int out_size, void* d_ws, size_t ws_size,
                              hipStream_t stream) {
  const float* x     = (const float*)d_in[0];
  const float* W1    = (const float*)d_in[1];
  // d_in[2] = b1: cancels exactly in training-mode BatchNorm -> unused
  const float* gamma = (const float*)d_in[3];
  const float* beta  = (const float*)d_in[4];
  const float* W2    = (const float*)d_in[5];
  const float* b2    = (const float*)d_in[6];
  const int*   src   = (const int*)d_in[7];
  const int*   dst   = (const int*)d_in[8];
  float* out = (float*)d_out;

  char* ws = (char*)d_ws;
  const size_t ABYTES = (size_t)MPAD * DD * 2;  // 51,380,224
  unsigned short* xin    = (unsigned short*)(ws);
  unsigned short* z      = (unsigned short*)(ws + ABYTES);
  unsigned short* h      = (unsigned short*)(ws + 2 * ABYTES);
  unsigned short* wb1    = (unsigned short*)(ws + 3 * ABYTES);
  unsigned short* wb2    = (unsigned short*)(ws + 3 * ABYTES + 2097152);
  int*            rowptr = (int*)(ws + 3 * ABYTES + 4194304);
  int*            cursor = (int*)(ws + 3 * ABYTES + 4494304);
  int*            csrc   = (int*)(ws + 3 * ABYTES + 4694304);
  float*          stats  = (float*)(ws + 3 * ABYTES + 5394304);
  float*          colsum = (float*)(ws + 3 * ABYTES + 5398400);
  float*          scsh   = (float*)(ws + 3 * ABYTES + 5402496);

  // weights -> bf16 (once)
  wconv_k<<<512, 256, 0, stream>>>(W1, W2, wb1, wb2);
  // zero xin pad rows once (agg never writes them; zeros keep stats/colsum exact)
  hipMemsetAsync(xin + (size_t)NN * DD, 0, (size_t)(MPAD - NN) * DD * 2, stream);

  // CSR build (once)
  hipMemsetAsync(cursor, 0, NN * sizeof(int), stream);
  count_k<<<(NE + 255) / 256, 256, 0, stream>>>(dst, cursor);
  scan_k<<<1, 1024, 0, stream>>>(cursor, rowptr, cursor);
  fill_k<<<(NE + 255) / 256, 256, 0, stream>>>(src, dst, cursor, csrc);

  hipMemsetAsync(colsum, 0, 2 * DD * sizeof(float), stream);
  hipMemsetAsync(stats, 0, 2 * DD * sizeof(float), stream);  // bnfin re-zeroes per layer

  dim3 gg(DD / 256, MPAD / 128);  // (2, 392)
  for (int l = 0; l < 4; ++l) {
    if (l == 0)
      agg_f32_k<<<NN / 4, 256, 0, stream>>>(x, rowptr, csrc, xin);
    else
      agg_bf16_k<<<NN / 4, 256, 0, stream>>>(h, rowptr, csrc, xin);
    gemm1_k<<<gg, 512, 0, stream>>>(xin, wb1 + (size_t)l * DD * DD, z, stats);
    bnfin_k<<<1, DD, 0, stream>>>(stats, gamma + l * DD, beta + l * DD, scsh);
    const int slot = (l == 2) ? 0 : ((l == 3) ? 1 : -1);
    gemm2_k<<<gg, 512, 0, stream>>>(z, wb2 + (size_t)l * DD * DD, scsh, b2 + l * DD,
                                    h, colsum + (slot == 1 ? DD : 0),
                                    (l < 3) ? 1 : 0, (slot >= 0) ? 1 : 0);
  }
  out_k<<<1, DD, 0, stream>>>(colsum, b2, out);
}

// Round 7
// 822.977 us; speedup vs baseline: 1.0721x; 1.0158x over previous
//
#include <hip/hip_runtime.h>

#define NN 50000
#define MPAD 50176  // 392 * 128
#define DD 512
#define NE 150000

typedef float f32x4 __attribute__((ext_vector_type(4)));
typedef float f32x8 __attribute__((ext_vector_type(8)));
typedef __bf16 bf16x8 __attribute__((ext_vector_type(8)));
typedef unsigned short u16x8 __attribute__((ext_vector_type(8)));

__device__ __forceinline__ void gload16(const void* g, void* l) {
  __builtin_amdgcn_global_load_lds((const __attribute__((address_space(1))) void*)g,
                                   (__attribute__((address_space(3))) void*)l, 16, 0, 0);
}

// read the 8 b128 fragments of one kk-half (T2-swizzled)
#define READ_FRAGS(la, lb, kk, AV, BV)                                                       \
  {                                                                                          \
    const int so = (((kk) * 4 + fg) ^ sx) * 8;                                               \
    _Pragma("unroll") for (int i = 0; i < 4; ++i)                                            \
        AV[i] = *reinterpret_cast<const bf16x8*>(&(la)[(rg + i * 16 + fr) * 64 + so]);       \
    _Pragma("unroll") for (int j = 0; j < 4; ++j)                                            \
        BV[j] = *reinterpret_cast<const bf16x8*>(&(lb)[(cg + j * 16 + fr) * 64 + so]);       \
  }

#define MFMA16(AV, BV)                                                                       \
  _Pragma("unroll") for (int i = 0; i < 4; ++i)                                              \
      _Pragma("unroll") for (int j = 0; j < 4; ++j)                                          \
          acc[i][j] = __builtin_amdgcn_mfma_f32_16x16x32_bf16(AV[i], BV[j], acc[i][j], 0, 0, 0);

#define PHASE_TAIL(AV, BV)                                                                   \
  __builtin_amdgcn_s_barrier();                                                              \
  asm volatile("s_waitcnt lgkmcnt(0)" ::: "memory");                                         \
  __builtin_amdgcn_sched_barrier(0);                                                         \
  __builtin_amdgcn_s_setprio(1);                                                             \
  MFMA16(AV, BV);                                                                            \
  __builtin_amdgcn_s_setprio(0);

// ============ weight convert: f32 -> bf16 ============
__global__ void wconv_k(const float* __restrict__ W1, const float* __restrict__ W2,
                        unsigned short* __restrict__ o1, unsigned short* __restrict__ o2) {
  const size_t i = ((size_t)blockIdx.x * 256 + threadIdx.x) * 8;
  {
    const f32x4* g = reinterpret_cast<const f32x4*>(W1 + i);
    f32x4 a = g[0], b = g[1];
    f32x8 v;
    v[0]=a[0]; v[1]=a[1]; v[2]=a[2]; v[3]=a[3]; v[4]=b[0]; v[5]=b[1]; v[6]=b[2]; v[7]=b[3];
    *reinterpret_cast<bf16x8*>(o1 + i) = __builtin_convertvector(v, bf16x8);
  }
  {
    const f32x4* g = reinterpret_cast<const f32x4*>(W2 + i);
    f32x4 a = g[0], b = g[1];
    f32x8 v;
    v[0]=a[0]; v[1]=a[1]; v[2]=a[2]; v[3]=a[3]; v[4]=b[0]; v[5]=b[1]; v[6]=b[2]; v[7]=b[3];
    *reinterpret_cast<bf16x8*>(o2 + i) = __builtin_convertvector(v, bf16x8);
  }
}

// ============ CSR build ============
__global__ void count_k(const int* __restrict__ dst, int* __restrict__ cnt) {
  const int e = blockIdx.x * 256 + threadIdx.x;
  if (e < NE) atomicAdd(&cnt[dst[e]], 1);
}

__global__ __launch_bounds__(1024) void scan_k(const int* __restrict__ cnt,
                                               int* __restrict__ rowptr,
                                               int* __restrict__ cursor) {
  __shared__ int wsum[16];
  __shared__ int base_s;
  if (threadIdx.x == 0) base_s = 0;
  __syncthreads();
  const int lane = threadIdx.x & 63;
  const int wid = threadIdx.x >> 6;
  for (int c0 = 0; c0 < NN; c0 += 1024) {
    const int i = c0 + threadIdx.x;
    const int v = (i < NN) ? cnt[i] : 0;
    int incl = v;
#pragma unroll
    for (int d = 1; d < 64; d <<= 1) {
      int t = __shfl_up(incl, d);
      if (lane >= d) incl += t;
    }
    if (lane == 63) wsum[wid] = incl;
    __syncthreads();
    if (wid == 0 && lane < 16) {
      int wv = wsum[lane];
#pragma unroll
      for (int d = 1; d < 16; d <<= 1) {
        int t = __shfl_up(wv, d);
        if (lane >= d) wv += t;
      }
      wsum[lane] = wv;
    }
    __syncthreads();
    const int waveoff = wid ? wsum[wid - 1] : 0;
    const int excl = base_s + waveoff + incl - v;
    if (i < NN) {
      rowptr[i] = excl;
      cursor[i] = excl;
    }
    __syncthreads();
    if (threadIdx.x == 0) base_s += wsum[15];
    __syncthreads();
  }
  if (threadIdx.x == 0) rowptr[NN] = base_s;
}

__global__ void fill_k(const int* __restrict__ src, const int* __restrict__ dst,
                       int* __restrict__ cursor, int* __restrict__ csrc) {
  const int e = blockIdx.x * 256 + threadIdx.x;
  if (e < NE) {
    const int pos = atomicAdd(&cursor[dst[e]], 1);
    csrc[pos] = src[e];
  }
}

// ============ aggregation ============
__global__ __launch_bounds__(256) void agg_f32_k(const float* __restrict__ h,
                                                 const int* __restrict__ rowptr,
                                                 const int* __restrict__ csrc,
                                                 unsigned short* __restrict__ xout) {
  const int node = blockIdx.x * 4 + (threadIdx.x >> 6);
  const int lane = threadIdx.x & 63;
  const f32x4* row = reinterpret_cast<const f32x4*>(h + (size_t)node * DD + lane * 8);
  f32x4 a0 = row[0], a1 = row[1];
  const int p1 = rowptr[node + 1];
  for (int p = rowptr[node]; p < p1; ++p) {
    const int s = csrc[p];
    const f32x4* rs = reinterpret_cast<const f32x4*>(h + (size_t)s * DD + lane * 8);
    a0 += rs[0];
    a1 += rs[1];
  }
  f32x8 vf;
  vf[0]=a0[0]; vf[1]=a0[1]; vf[2]=a0[2]; vf[3]=a0[3];
  vf[4]=a1[0]; vf[5]=a1[1]; vf[6]=a1[2]; vf[7]=a1[3];
  *reinterpret_cast<bf16x8*>(xout + (size_t)node * DD + lane * 8) =
      __builtin_convertvector(vf, bf16x8);
}

__global__ __launch_bounds__(256) void agg_bf16_k(const unsigned short* __restrict__ h,
                                                  const int* __restrict__ rowptr,
                                                  const int* __restrict__ csrc,
                                                  unsigned short* __restrict__ xout) {
  const int node = blockIdx.x * 4 + (threadIdx.x >> 6);
  const int lane = threadIdx.x & 63;
  u16x8 sv = *reinterpret_cast<const u16x8*>(h + (size_t)node * DD + lane * 8);
  f32x8 acc = __builtin_convertvector(__builtin_bit_cast(bf16x8, sv), f32x8);
  const int p1 = rowptr[node + 1];
  for (int p = rowptr[node]; p < p1; ++p) {
    const int s = csrc[p];
    u16x8 rv = *reinterpret_cast<const u16x8*>(h + (size_t)s * DD + lane * 8);
    acc += __builtin_convertvector(__builtin_bit_cast(bf16x8, rv), f32x8);
  }
  *reinterpret_cast<bf16x8*>(xout + (size_t)node * DD + lane * 8) =
      __builtin_convertvector(acc, bf16x8);
}

// ============ GEMM1: Z = bf16( xin @ W1bf^T ), stats += colsum(z), colsum(z^2) ============
// 128x256 tile, 8 waves, 3-ring, counted vmcnt(6), 2-phase-per-K-tile interleave (T3/T4/T5),
// T2 swizzle, bijective XCD blockIdx swizzle (784 = 8*98).
__global__ __launch_bounds__(512, 2) void gemm1_k(
    const unsigned short* __restrict__ A, const unsigned short* __restrict__ B,
    unsigned short* __restrict__ Z, float* __restrict__ stats) {
  // memory order [A0][A2][A1][B0][B2][B1]; epilogue C (64KB @24576) covers B-ring0+ring2
  __shared__ unsigned short sm[73728];  // 144 KB
  constexpr int AOFF[3] = {0, 16384, 8192};
  constexpr int BOFF[3] = {24576, 57344, 40960};
  const int tid = threadIdx.x;
  const int lane = tid & 63;
  const int w = tid >> 6;
  const int rg = (w >> 2) * 64;
  const int cg = (w & 3) * 64;
  const int fr = lane & 15;
  const int fg = lane >> 4;
  const int sx = fr & 7;
  const int bid = blockIdx.x;
  const int swb = (bid & 7) * 98 + (bid >> 3);  // XCD-contiguous row bands
  const int brow = (swb >> 1) * 128;
  const int bcol = (swb & 1) * 256;
  const char* Ab = (const char*)A + (size_t)brow * 1024;
  const char* Bb = (const char*)B + (size_t)bcol * 1024;
  const int srow = tid >> 3;
  const int sce = (tid & 7) * 8;                     // linear LDS dest (elems)
  const int sswz = (((tid & 7) ^ (srow & 7))) * 16;  // pre-swizzled global slot (bytes)

  f32x4 acc[4][4] = {};

  // prologue: stage tiles 0,1 (12 gloads in flight)
#pragma unroll
  for (int t = 0; t < 2; ++t) {
#pragma unroll
    for (int i = 0; i < 2; ++i)
      gload16(Ab + (size_t)(i * 64 + srow) * 1024 + t * 128 + sswz,
              &sm[AOFF[t] + (i * 64 + srow) * 64 + sce]);
#pragma unroll
    for (int i = 0; i < 4; ++i)
      gload16(Bb + (size_t)(i * 64 + srow) * 1024 + t * 128 + sswz,
              &sm[BOFF[t] + (i * 64 + srow) * 64 + sce]);
  }

#pragma unroll
  for (int kt = 0; kt < 8; ++kt) {
    if (kt < 7) asm volatile("s_waitcnt vmcnt(6)" ::: "memory");
    else        asm volatile("s_waitcnt vmcnt(0)" ::: "memory");
    __builtin_amdgcn_s_barrier();
    const unsigned short* la = &sm[AOFF[kt % 3]];
    const unsigned short* lb = &sm[BOFF[kt % 3]];
    bf16x8 av[4], bv[4];
    // ---- phase 0: kk0 frags + first half of dist-2 stage ----
    READ_FRAGS(la, lb, 0, av, bv);
    if (kt + 2 < 8) {
      const int t2 = kt + 2;
#pragma unroll
      for (int i = 0; i < 2; ++i)
        gload16(Ab + (size_t)(i * 64 + srow) * 1024 + t2 * 128 + sswz,
                &sm[AOFF[t2 % 3] + (i * 64 + srow) * 64 + sce]);
      gload16(Bb + (size_t)srow * 1024 + t2 * 128 + sswz,
              &sm[BOFF[t2 % 3] + srow * 64 + sce]);
    }
    PHASE_TAIL(av, bv)
    __builtin_amdgcn_s_barrier();
    // ---- phase 1: kk1 frags + second half of stage ----
    READ_FRAGS(la, lb, 1, av, bv);
    if (kt + 2 < 8) {
      const int t2 = kt + 2;
#pragma unroll
      for (int i = 1; i < 4; ++i)
        gload16(Bb + (size_t)(i * 64 + srow) * 1024 + t2 * 128 + sswz,
                &sm[BOFF[t2 % 3] + (i * 64 + srow) * 64 + sce]);
    }
    PHASE_TAIL(av, bv)
    // closing barrier = next iter's top barrier
  }

  // stats (from acc regs; pad rows contribute 0)
#pragma unroll
  for (int j = 0; j < 4; ++j) {
    const int col = bcol + cg + j * 16 + fr;
    float s1 = 0.f, s2 = 0.f;
#pragma unroll
    for (int i = 0; i < 4; ++i)
#pragma unroll
      for (int r = 0; r < 4; ++r) {
        const float v = acc[i][j][r];
        s1 += v;
        s2 += v * v;
      }
    s1 += __shfl_down(s1, 32);
    s2 += __shfl_down(s2, 32);
    s1 += __shfl_down(s1, 16);
    s2 += __shfl_down(s2, 16);
    if (lane < 16) {
      atomicAdd(&stats[col], s1);
      atomicAdd(&stats[DD + col], s2);
    }
  }

  // LDS-staged C write (swizzled: phys 16B-slot = logical ^ (row&7))
  unsigned short* C = &sm[24576];
#pragma unroll
  for (int j = 0; j < 4; ++j)
#pragma unroll
    for (int i = 0; i < 4; ++i)
#pragma unroll
      for (int r = 0; r < 4; ++r) {
        const int row = rg + i * 16 + fg * 4 + r;
        const int col = cg + j * 16 + fr;
        __bf16 b = (__bf16)acc[i][j][r];
        C[row * 256 + (((col >> 3) ^ (row & 7)) << 3) + (col & 7)] =
            __builtin_bit_cast(unsigned short, b);
      }
  asm volatile("s_waitcnt lgkmcnt(0)" ::: "memory");
  __builtin_amdgcn_s_barrier();
  const int orow = tid >> 2;
  const int ox = orow & 7;
  const unsigned short* cr = &C[orow * 256];
  unsigned short* zg = Z + (size_t)(brow + orow) * DD + bcol;
#pragma unroll
  for (int i = 0; i < 8; ++i) {
    const int s = (tid & 3) * 8 + ((i + tid) & 7);  // logical 16B slot 0..31
    *reinterpret_cast<u16x8*>(zg + s * 8) = *reinterpret_cast<const u16x8*>(cr + (s ^ ox) * 8);
  }
}

// ============ BN finalize (+ re-zero stats for next layer) ============
__global__ void bnfin_k(float* __restrict__ stats, const float* __restrict__ gamma,
                        const float* __restrict__ beta, float* __restrict__ scsh) {
  const int n = threadIdx.x;
  const float inv = 1.0f / (float)NN;
  const float mu = stats[n] * inv;
  const float var = stats[DD + n] * inv - mu * mu;
  const float sc = rsqrtf(var + 1e-5f) * gamma[n];
  scsh[n] = sc;
  scsh[DD + n] = beta[n] - mu * sc;
  stats[n] = 0.f;
  stats[DD + n] = 0.f;
}

// BN+ReLU transform of two z-rows -> bf16 -> ds_write into A buffer (swizzled offset woff)
__device__ __forceinline__ void bn_stage(u16x8 z0v, u16x8 z1v, bool v0, bool v1,
                                         const float* sc_base, int c0,
                                         unsigned short* adst, int srow, int woff) {
  f32x4 sca = *reinterpret_cast<const f32x4*>(sc_base + c0);
  f32x4 scb = *reinterpret_cast<const f32x4*>(sc_base + c0 + 4);
  f32x4 sha = *reinterpret_cast<const f32x4*>(sc_base + 512 + c0);
  f32x4 shb = *reinterpret_cast<const f32x4*>(sc_base + 512 + c0 + 4);
  f32x8 f0 = __builtin_convertvector(__builtin_bit_cast(bf16x8, z0v), f32x8);
  f32x8 f1 = __builtin_convertvector(__builtin_bit_cast(bf16x8, z1v), f32x8);
  f32x8 a0 = {}, a1 = {};
  if (v0) {
#pragma unroll
    for (int q = 0; q < 4; ++q) {
      a0[q]     = fmaxf(f0[q]     * sca[q] + sha[q], 0.f);
      a0[q + 4] = fmaxf(f0[q + 4] * scb[q] + shb[q], 0.f);
    }
  }
  if (v1) {
#pragma unroll
    for (int q = 0; q < 4; ++q) {
      a1[q]     = fmaxf(f1[q]     * sca[q] + sha[q], 0.f);
      a1[q + 4] = fmaxf(f1[q + 4] * scb[q] + shb[q], 0.f);
    }
  }
  *reinterpret_cast<bf16x8*>(adst + srow * 64 + woff) = __builtin_convertvector(a0, bf16x8);
  *reinterpret_cast<bf16x8*>(adst + (srow + 64) * 64 + woff) = __builtin_convertvector(a1, bf16x8);
}

// ============ GEMM2: H = bf16(relu(z*sc+sh) @ W2bf^T + b2), fused colsum ============
// A reg-staged (BN+ReLU fused, dist-2 z prefetch), B 3-ring, vmcnt(6), 2-phase interleave.
__global__ __launch_bounds__(512, 2) void gemm2_k(
    const unsigned short* __restrict__ Zin, const unsigned short* __restrict__ B,
    const float* __restrict__ scshG, const float* __restrict__ b2,
    unsigned short* __restrict__ H, float* __restrict__ colsum,
    const int write_h, const int do_colsum) {
  __shared__ char smc[135168];  // A 2x16KB + B 3x32KB (+C overlay) + 4KB scsh
  unsigned short* sm = (unsigned short*)smc;
  float* lsc = (float*)(smc + 131072);
  constexpr int AOFF[2] = {0, 8192};
  constexpr int BOFF[3] = {16384, 49152, 32768};  // order [B0][B2][B1]
  const int tid = threadIdx.x;
  const int lane = tid & 63;
  const int w = tid >> 6;
  const int rg = (w >> 2) * 64;
  const int cg = (w & 3) * 64;
  const int fr = lane & 15;
  const int fg = lane >> 4;
  const int sx = fr & 7;
  const int bid = blockIdx.x;
  const int swb = (bid & 7) * 98 + (bid >> 3);
  const int brow = (swb >> 1) * 128;
  const int bcol = (swb & 1) * 256;
  const char* Bb = (const char*)B + (size_t)bcol * 1024;
  const int srow = tid >> 3;
  const int sce = (tid & 7) * 8;
  const int sswz = (((tid & 7) ^ (srow & 7))) * 16;
  const int wsz  = (((tid & 7) ^ (srow & 7))) * 8;
  const int r0 = brow + srow;
  const int r1 = r0 + 64;
  const bool v0 = r0 < NN;
  const bool v1 = r1 < NN;
  const unsigned short* zrow0 = Zin + (size_t)r0 * DD + sce;
  const unsigned short* zrow1 = Zin + (size_t)r1 * DD + sce;

  f32x4 acc[4][4] = {};
  u16x8 zE0, zE1, zO0, zO1;

  // ---- prologue ----
  zE0 = *reinterpret_cast<const u16x8*>(zrow0);       // z tile 0
  zE1 = *reinterpret_cast<const u16x8*>(zrow1);
  lsc[tid * 2] = scshG[tid * 2];                      // scsh -> LDS
  lsc[tid * 2 + 1] = scshG[tid * 2 + 1];
  bn_stage(zE0, zE1, v0, v1, scshG, sce, &sm[AOFF[0]], srow, wsz);
#pragma unroll
  for (int i = 0; i < 4; ++i)                         // B(0)
    gload16(Bb + (size_t)(i * 64 + srow) * 1024 + 0 * 128 + sswz,
            &sm[BOFF[0] + (i * 64 + srow) * 64 + sce]);
  zO0 = *reinterpret_cast<const u16x8*>(zrow0 + 64);  // z tile 1
  zO1 = *reinterpret_cast<const u16x8*>(zrow1 + 64);
#pragma unroll
  for (int i = 0; i < 4; ++i)                         // B(1)
    gload16(Bb + (size_t)(i * 64 + srow) * 1024 + 1 * 128 + sswz,
            &sm[BOFF[1] + (i * 64 + srow) * 64 + sce]);
  asm volatile("s_waitcnt lgkmcnt(0)" ::: "memory");  // lsc + A0 ds_writes visible

  // steady-state FIFO at kt top: [B(kt):4, z(kt+1):2, B(kt+1):4] -> gate vmcnt(6)
#pragma unroll
  for (int kt = 0; kt < 8; ++kt) {
    if (kt < 7) asm volatile("s_waitcnt vmcnt(6)" ::: "memory");
    else        asm volatile("s_waitcnt vmcnt(0)" ::: "memory");
    __builtin_amdgcn_s_barrier();
    const unsigned short* la = &sm[AOFF[kt & 1]];
    const unsigned short* lb = &sm[BOFF[kt % 3]];
    bf16x8 av[4], bv[4];
    // ---- phase 0: kk0 frags + BN-stage A(kt+1) ----
    READ_FRAGS(la, lb, 0, av, bv);
    if (kt + 1 < 8) {
      if ((kt & 1) == 0)
        bn_stage(zO0, zO1, v0, v1, lsc, (kt + 1) * 64 + sce, &sm[AOFF[(kt + 1) & 1]], srow, wsz);
      else
        bn_stage(zE0, zE1, v0, v1, lsc, (kt + 1) * 64 + sce, &sm[AOFF[(kt + 1) & 1]], srow, wsz);
    }
    PHASE_TAIL(av, bv)
    __builtin_amdgcn_s_barrier();
    // ---- phase 1: kk1 frags + z(kt+2) reg loads + B(kt+2) gloads ----
    READ_FRAGS(la, lb, 1, av, bv);
    if (kt + 2 < 8) {
      const int t2 = kt + 2;
      if ((kt & 1) == 0) {
        zE0 = *reinterpret_cast<const u16x8*>(zrow0 + t2 * 64);
        zE1 = *reinterpret_cast<const u16x8*>(zrow1 + t2 * 64);
      } else {
        zO0 = *reinterpret_cast<const u16x8*>(zrow0 + t2 * 64);
        zO1 = *reinterpret_cast<const u16x8*>(zrow1 + t2 * 64);
      }
#pragma unroll
      for (int i = 0; i < 4; ++i)
        gload16(Bb + (size_t)(i * 64 + srow) * 1024 + t2 * 128 + sswz,
                &sm[BOFF[t2 % 3] + (i * 64 + srow) * 64 + sce]);
    }
    PHASE_TAIL(av, bv)
  }

  // colsum (pre-bias, from acc; pad rows contribute 0)
  if (do_colsum) {
#pragma unroll
    for (int j = 0; j < 4; ++j) {
      const int col = bcol + cg + j * 16 + fr;
      float s1 = 0.f;
#pragma unroll
      for (int i = 0; i < 4; ++i)
#pragma unroll
        for (int r = 0; r < 4; ++r) s1 += acc[i][j][r];
      s1 += __shfl_down(s1, 32);
      s1 += __shfl_down(s1, 16);
      if (lane < 16) atomicAdd(&colsum[col], s1);
    }
  }

  if (write_h) {  // LDS-staged H write (+b2), swizzled, coalesced
    unsigned short* C = &sm[16384];
#pragma unroll
    for (int j = 0; j < 4; ++j) {
      const float bb = b2[bcol + cg + j * 16 + fr];
#pragma unroll
      for (int i = 0; i < 4; ++i)
#pragma unroll
        for (int r = 0; r < 4; ++r) {
          const int row = rg + i * 16 + fg * 4 + r;
          const int col = cg + j * 16 + fr;
          __bf16 b = (__bf16)(acc[i][j][r] + bb);
          C[row * 256 + (((col >> 3) ^ (row & 7)) << 3) + (col & 7)] =
              __builtin_bit_cast(unsigned short, b);
        }
    }
    asm volatile("s_waitcnt lgkmcnt(0)" ::: "memory");
    __builtin_amdgcn_s_barrier();
    const int orow = tid >> 2;
    const int ox = orow & 7;
    const unsigned short* cr = &C[orow * 256];
    unsigned short* hg = H + (size_t)(brow + orow) * DD + bcol;
#pragma unroll
    for (int i = 0; i < 8; ++i) {
      const int s = (tid & 3) * 8 + ((i + tid) & 7);
      *reinterpret_cast<u16x8*>(hg + s * 8) = *reinterpret_cast<const u16x8*>(cr + (s ^ ox) * 8);
    }
  }
}

// ============ final outputs ============
__global__ void out_k(const float* __restrict__ colsum, const float* __restrict__ b2_all,
                      float* __restrict__ out) {
  const int n = threadIdx.x;
  const float inv = 1.0f / (float)NN;
  out[n]      = colsum[DD + n] * inv + b2_all[3 * DD + n];  // outs[-1] = layer 3
  out[DD + n] = colsum[n] * inv      + b2_all[2 * DD + n];  // outs[-2] = layer 2
}

extern "C" void kernel_launch(void* const* d_in, const int* in_sizes, int n_in,
                              void* d_out, int out_size, void* d_ws, size_t ws_size,
                              hipStream_t stream) {
  const float* x     = (const float*)d_in[0];
  const float* W1    = (const float*)d_in[1];
  // d_in[2] = b1: cancels exactly in training-mode BatchNorm -> unused
  const float* gamma = (const float*)d_in[3];
  const float* beta  = (const float*)d_in[4];
  const float* W2    = (const float*)d_in[5];
  const float* b2    = (const float*)d_in[6];
  const int*   src   = (const int*)d_in[7];
  const int*   dst   = (const int*)d_in[8];
  float* out = (float*)d_out;

  char* ws = (char*)d_ws;
  const size_t ABYTES = (size_t)MPAD * DD * 2;  // 51,380,224
  unsigned short* xin    = (unsigned short*)(ws);
  unsigned short* z      = (unsigned short*)(ws + ABYTES);
  unsigned short* h      = (unsigned short*)(ws + 2 * ABYTES);
  unsigned short* wb1    = (unsigned short*)(ws + 3 * ABYTES);
  unsigned short* wb2    = (unsigned short*)(ws + 3 * ABYTES + 2097152);
  int*            rowptr = (int*)(ws + 3 * ABYTES + 4194304);
  int*            cursor = (int*)(ws + 3 * ABYTES + 4494304);
  int*            csrc   = (int*)(ws + 3 * ABYTES + 4694304);
  float*          stats  = (float*)(ws + 3 * ABYTES + 5394304);
  float*          colsum = (float*)(ws + 3 * ABYTES + 5398400);
  float*          scsh   = (float*)(ws + 3 * ABYTES + 5402496);

  // weights -> bf16 (once)
  wconv_k<<<512, 256, 0, stream>>>(W1, W2, wb1, wb2);
  // zero xin pad rows once (agg never writes them; zeros keep stats/colsum exact)
  hipMemsetAsync(xin + (size_t)NN * DD, 0, (size_t)(MPAD - NN) * DD * 2, stream);

  // CSR build (once)
  hipMemsetAsync(cursor, 0, NN * sizeof(int), stream);
  count_k<<<(NE + 255) / 256, 256, 0, stream>>>(dst, cursor);
  scan_k<<<1, 1024, 0, stream>>>(cursor, rowptr, cursor);
  fill_k<<<(NE + 255) / 256, 256, 0, stream>>>(src, dst, cursor, csrc);

  hipMemsetAsync(colsum, 0, 2 * DD * sizeof(float), stream);
  hipMemsetAsync(stats, 0, 2 * DD * sizeof(float), stream);  // bnfin re-zeroes per layer

  for (int l = 0; l < 4; ++l) {
    if (l == 0)
      agg_f32_k<<<NN / 4, 256, 0, stream>>>(x, rowptr, csrc, xin);
    else
      agg_bf16_k<<<NN / 4, 256, 0, stream>>>(h, rowptr, csrc, xin);
    gemm1_k<<<784, 512, 0, stream>>>(xin, wb1 + (size_t)l * DD * DD, z, stats);
    bnfin_k<<<1, DD, 0, stream>>>(stats, gamma + l * DD, beta + l * DD, scsh);
    const int slot = (l == 2) ? 0 : ((l == 3) ? 1 : -1);
    gemm2_k<<<784, 512, 0, stream>>>(z, wb2 + (size_t)l * DD * DD, scsh, b2 + l * DD,
                                     h, colsum + (slot == 1 ? DD : 0),
                                     (l < 3) ? 1 : 0, (slot >= 0) ? 1 : 0);
  }
  out_k<<<1, DD, 0, stream>>>(colsum, b2, out);
}

// Round 8
// 682.111 us; speedup vs baseline: 1.2935x; 1.2065x over previous
//
#include <hip/hip_runtime.h>

#define NN 50000
#define MPAD 50176  // 392 * 128
#define DD 512
#define NE 150000

typedef float f32x4 __attribute__((ext_vector_type(4)));
typedef float f32x8 __attribute__((ext_vector_type(8)));
typedef __bf16 bf16x8 __attribute__((ext_vector_type(8)));
typedef unsigned short u16x8 __attribute__((ext_vector_type(8)));

__device__ __forceinline__ void gload16(const void* g, void* l) {
  __builtin_amdgcn_global_load_lds((const __attribute__((address_space(1))) void*)g,
                                   (__attribute__((address_space(3))) void*)l, 16, 0, 0);
}

// read the 8 b128 fragments of one kk-half (T2-swizzled)
#define READ_FRAGS(la, lb, kk, AV, BV)                                                       \
  {                                                                                          \
    const int so = (((kk) * 4 + fg) ^ sx) * 8;                                               \
    _Pragma("unroll") for (int i = 0; i < 4; ++i)                                            \
        AV[i] = *reinterpret_cast<const bf16x8*>(&(la)[(rg + i * 16 + fr) * 64 + so]);       \
    _Pragma("unroll") for (int j = 0; j < 4; ++j)                                            \
        BV[j] = *reinterpret_cast<const bf16x8*>(&(lb)[(cg + j * 16 + fr) * 64 + so]);       \
  }

#define MFMA16(AV, BV)                                                                       \
  _Pragma("unroll") for (int i = 0; i < 4; ++i)                                              \
      _Pragma("unroll") for (int j = 0; j < 4; ++j)                                          \
          acc[i][j] = __builtin_amdgcn_mfma_f32_16x16x32_bf16(AV[i], BV[j], acc[i][j], 0, 0, 0);

#define PHASE_TAIL(AV, BV)                                                                   \
  __builtin_amdgcn_s_barrier();                                                              \
  asm volatile("s_waitcnt lgkmcnt(0)" ::: "memory");                                         \
  __builtin_amdgcn_sched_barrier(0);                                                         \
  __builtin_amdgcn_s_setprio(1);                                                             \
  MFMA16(AV, BV);                                                                            \
  __builtin_amdgcn_s_setprio(0);

// ============ W1 layer-0 convert: f32 -> bf16 ============
__global__ void wconv0_k(const float* __restrict__ W1, unsigned short* __restrict__ o1) {
  const size_t i = ((size_t)blockIdx.x * 256 + threadIdx.x) * 8;
  const f32x4* g = reinterpret_cast<const f32x4*>(W1 + i);
  f32x4 a = g[0], b = g[1];
  f32x8 v;
  v[0]=a[0]; v[1]=a[1]; v[2]=a[2]; v[3]=a[3]; v[4]=b[0]; v[5]=b[1]; v[6]=b[2]; v[7]=b[3];
  *reinterpret_cast<bf16x8*>(o1 + i) = __builtin_convertvector(v, bf16x8);
}

// ============ W2 transpose (layers 0..2): W2T[l][b][a] = W2[l][a][b] ============
__global__ __launch_bounds__(256) void trans_k(const float* __restrict__ W2,
                                               float* __restrict__ W2T) {
  __shared__ float t[64][65];
  const int l = blockIdx.z;
  const int a0 = blockIdx.x * 64;
  const int b0 = blockIdx.y * 64;
  const float* src = W2 + (size_t)l * DD * DD;
  float* dst = W2T + (size_t)l * DD * DD;
#pragma unroll
  for (int q = 0; q < 16; ++q) {
    const int idx = q * 256 + threadIdx.x;
    const int r = idx >> 6, c = idx & 63;
    t[r][c] = src[(size_t)(a0 + r) * DD + b0 + c];
  }
  __syncthreads();
#pragma unroll
  for (int q = 0; q < 16; ++q) {
    const int idx = q * 256 + threadIdx.x;
    const int r = idx >> 6, c = idx & 63;
    dst[(size_t)(b0 + r) * DD + a0 + c] = t[c][r];
  }
}

// ============ Wf_l = W1_{l+1} @ W2_l  (bf16 out), l = 0..2 ============
// C[n,b] = sum_a W1[l+1][n,a] * W2T[l][b,a]; simple 128x128 MFMA tile (one-off).
__global__ __launch_bounds__(256) void wfuse_k(const float* __restrict__ W1all,
                                               const float* __restrict__ W2T,
                                               unsigned short* __restrict__ WF) {
  constexpr int LDK = 72;
  __shared__ unsigned short lA[128 * LDK];
  __shared__ unsigned short lB[128 * LDK];
  const int l = blockIdx.z;
  const float* A = W1all + (size_t)(l + 1) * DD * DD;
  const float* Bt = W2T + (size_t)l * DD * DD;
  unsigned short* out = WF + (size_t)l * DD * DD;
  const int tid = threadIdx.x;
  const int brow = blockIdx.y * 128;
  const int bcol = blockIdx.x * 128;
  const int lane = tid & 63;
  const int w = tid >> 6;
  const int wr = (w >> 1) * 64;
  const int wc = (w & 1) * 64;
  const int fr = lane & 15;
  const int fg = lane >> 4;
  f32x4 acc[4][4] = {};
  const int srow = tid >> 3;
  const int scol = (tid & 7) * 8;
  for (int kt = 0; kt < 8; ++kt) {
    const int k0 = kt * 64 + scol;
    __syncthreads();
#pragma unroll
    for (int p = 0; p < 4; ++p) {
      const int r = srow + 32 * p;
      {
        const f32x4* g = reinterpret_cast<const f32x4*>(A + (size_t)(brow + r) * DD + k0);
        f32x4 v0 = g[0], v1 = g[1];
        f32x8 vf;
        vf[0]=v0[0]; vf[1]=v0[1]; vf[2]=v0[2]; vf[3]=v0[3];
        vf[4]=v1[0]; vf[5]=v1[1]; vf[6]=v1[2]; vf[7]=v1[3];
        *reinterpret_cast<bf16x8*>(&lA[r * LDK + scol]) = __builtin_convertvector(vf, bf16x8);
      }
      {
        const f32x4* g = reinterpret_cast<const f32x4*>(Bt + (size_t)(bcol + r) * DD + k0);
        f32x4 v0 = g[0], v1 = g[1];
        f32x8 vf;
        vf[0]=v0[0]; vf[1]=v0[1]; vf[2]=v0[2]; vf[3]=v0[3];
        vf[4]=v1[0]; vf[5]=v1[1]; vf[6]=v1[2]; vf[7]=v1[3];
        *reinterpret_cast<bf16x8*>(&lB[r * LDK + scol]) = __builtin_convertvector(vf, bf16x8);
      }
    }
    __syncthreads();
#pragma unroll
    for (int kk = 0; kk < 2; ++kk) {
      bf16x8 av[4], bv[4];
#pragma unroll
      for (int i = 0; i < 4; ++i)
        av[i] = *reinterpret_cast<const bf16x8*>(&lA[(wr + i * 16 + fr) * LDK + kk * 32 + fg * 8]);
#pragma unroll
      for (int j = 0; j < 4; ++j)
        bv[j] = *reinterpret_cast<const bf16x8*>(&lB[(wc + j * 16 + fr) * LDK + kk * 32 + fg * 8]);
#pragma unroll
      for (int i = 0; i < 4; ++i)
#pragma unroll
        for (int j = 0; j < 4; ++j)
          acc[i][j] = __builtin_amdgcn_mfma_f32_16x16x32_bf16(av[i], bv[j], acc[i][j], 0, 0, 0);
    }
  }
#pragma unroll
  for (int j = 0; j < 4; ++j) {
    const int col = bcol + wc + j * 16 + fr;
#pragma unroll
    for (int i = 0; i < 4; ++i) {
      const int rb = brow + wr + i * 16 + fg * 4;
#pragma unroll
      for (int r = 0; r < 4; ++r) {
        __bf16 b = (__bf16)acc[i][j][r];
        out[(size_t)(rb + r) * DD + col] = __builtin_bit_cast(unsigned short, b);
      }
    }
  }
}

// ============ c_l = W1_{l+1} @ b2_l  (f32), l = 0..2 ============
__global__ __launch_bounds__(512) void cvec_k(const float* __restrict__ W1all,
                                              const float* __restrict__ b2all,
                                              float* __restrict__ cvec) {
  __shared__ float bb[DD];
  const int l = blockIdx.x;
  bb[threadIdx.x] = b2all[(size_t)l * DD + threadIdx.x];
  __syncthreads();
  const float* row = W1all + (size_t)(l + 1) * DD * DD + (size_t)threadIdx.x * DD;
  float s = 0.f;
  for (int a = 0; a < DD; a += 4) {
    f32x4 v = *reinterpret_cast<const f32x4*>(row + a);
    s += v[0] * bb[a] + v[1] * bb[a + 1] + v[2] * bb[a + 2] + v[3] * bb[a + 3];
  }
  cvec[l * DD + threadIdx.x] = s;
}

// ============ CSR build ============
__global__ void count_k(const int* __restrict__ dst, int* __restrict__ cnt) {
  const int e = blockIdx.x * 256 + threadIdx.x;
  if (e < NE) atomicAdd(&cnt[dst[e]], 1);
}

__global__ __launch_bounds__(1024) void scan_k(const int* __restrict__ cnt,
                                               int* __restrict__ rowptr,
                                               int* __restrict__ cursor) {
  __shared__ int wsum[16];
  __shared__ int base_s;
  if (threadIdx.x == 0) base_s = 0;
  __syncthreads();
  const int lane = threadIdx.x & 63;
  const int wid = threadIdx.x >> 6;
  for (int c0 = 0; c0 < NN; c0 += 1024) {
    const int i = c0 + threadIdx.x;
    const int v = (i < NN) ? cnt[i] : 0;
    int incl = v;
#pragma unroll
    for (int d = 1; d < 64; d <<= 1) {
      int t = __shfl_up(incl, d);
      if (lane >= d) incl += t;
    }
    if (lane == 63) wsum[wid] = incl;
    __syncthreads();
    if (wid == 0 && lane < 16) {
      int wv = wsum[lane];
#pragma unroll
      for (int d = 1; d < 16; d <<= 1) {
        int t = __shfl_up(wv, d);
        if (lane >= d) wv += t;
      }
      wsum[lane] = wv;
    }
    __syncthreads();
    const int waveoff = wid ? wsum[wid - 1] : 0;
    const int excl = base_s + waveoff + incl - v;
    if (i < NN) {
      rowptr[i] = excl;
      cursor[i] = excl;
    }
    __syncthreads();
    if (threadIdx.x == 0) base_s += wsum[15];
    __syncthreads();
  }
  if (threadIdx.x == 0) rowptr[NN] = base_s;
}

__global__ void fill_k(const int* __restrict__ src, const int* __restrict__ dst,
                       int* __restrict__ cursor, int* __restrict__ csrc) {
  const int e = blockIdx.x * 256 + threadIdx.x;
  if (e < NE) {
    const int pos = atomicAdd(&cursor[dst[e]], 1);
    csrc[pos] = src[e];
  }
}

// ============ degp1[v] = 1 + in-degree(v); pad rows -> 0 ============
__global__ void degp1_k(const int* __restrict__ rowptr, float* __restrict__ degp1) {
  const int i = blockIdx.x * 256 + threadIdx.x;
  if (i < MPAD) degp1[i] = (i < NN) ? (float)(1 + rowptr[i + 1] - rowptr[i]) : 0.f;
}

// ============ layer-0 aggregation: xact[v] = bf16( x[v] + sum_u x[u] ) ============
__global__ __launch_bounds__(256) void agg_f32_k(const float* __restrict__ h,
                                                 const int* __restrict__ rowptr,
                                                 const int* __restrict__ csrc,
                                                 unsigned short* __restrict__ xout) {
  const int node = blockIdx.x * 4 + (threadIdx.x >> 6);
  const int lane = threadIdx.x & 63;
  const f32x4* row = reinterpret_cast<const f32x4*>(h + (size_t)node * DD + lane * 8);
  f32x4 a0 = row[0], a1 = row[1];
  const int p1 = rowptr[node + 1];
  for (int p = rowptr[node]; p < p1; ++p) {
    const int s = csrc[p];
    const f32x4* rs = reinterpret_cast<const f32x4*>(h + (size_t)s * DD + lane * 8);
    a0 += rs[0];
    a1 += rs[1];
  }
  f32x8 vf;
  vf[0]=a0[0]; vf[1]=a0[1]; vf[2]=a0[2]; vf[3]=a0[3];
  vf[4]=a1[0]; vf[5]=a1[1]; vf[6]=a1[2]; vf[7]=a1[3];
  *reinterpret_cast<bf16x8*>(xout + (size_t)node * DD + lane * 8) =
      __builtin_convertvector(vf, bf16x8);
}

// ============ boundary aggregation: xact[v] = bf16( act(z[v]) + sum_u act(z[u]) ) ============
// act(z) = relu(z*sc + sh) per column (elementwise -> commutes with the gather).
__global__ __launch_bounds__(256) void agg_act_k(const unsigned short* __restrict__ z,
                                                 const float* __restrict__ scsh,
                                                 const int* __restrict__ rowptr,
                                                 const int* __restrict__ csrc,
                                                 unsigned short* __restrict__ xout) {
  const int node = blockIdx.x * 4 + (threadIdx.x >> 6);
  const int lane = threadIdx.x & 63;
  const int c0 = lane * 8;
  f32x4 sca = *reinterpret_cast<const f32x4*>(scsh + c0);
  f32x4 scb = *reinterpret_cast<const f32x4*>(scsh + c0 + 4);
  f32x4 sha = *reinterpret_cast<const f32x4*>(scsh + DD + c0);
  f32x4 shb = *reinterpret_cast<const f32x4*>(scsh + DD + c0 + 4);
  u16x8 sv = *reinterpret_cast<const u16x8*>(z + (size_t)node * DD + c0);
  f32x8 f = __builtin_convertvector(__builtin_bit_cast(bf16x8, sv), f32x8);
  f32x8 acc;
#pragma unroll
  for (int q = 0; q < 4; ++q) {
    acc[q]     = fmaxf(f[q]     * sca[q] + sha[q], 0.f);
    acc[q + 4] = fmaxf(f[q + 4] * scb[q] + shb[q], 0.f);
  }
  const int p1 = rowptr[node + 1];
  for (int p = rowptr[node]; p < p1; ++p) {
    const int s = csrc[p];
    u16x8 rv = *reinterpret_cast<const u16x8*>(z + (size_t)s * DD + c0);
    f32x8 g = __builtin_convertvector(__builtin_bit_cast(bf16x8, rv), f32x8);
#pragma unroll
    for (int q = 0; q < 4; ++q) {
      acc[q]     += fmaxf(g[q]     * sca[q] + sha[q], 0.f);
      acc[q + 4] += fmaxf(g[q + 4] * scb[q] + shb[q], 0.f);
    }
  }
  *reinterpret_cast<bf16x8*>(xout + (size_t)node * DD + c0) =
      __builtin_convertvector(acc, bf16x8);
}

// ============ colsum of act(z) over real rows -> cs[512] ============
__global__ __launch_bounds__(256) void colsum_act_k(const unsigned short* __restrict__ z,
                                                    const float* __restrict__ scsh,
                                                    float* __restrict__ cs) {
  __shared__ float red[4][DD];
  const int g = threadIdx.x >> 6;
  const int lane = threadIdx.x & 63;
  const int c0 = lane * 8;
  f32x4 sca = *reinterpret_cast<const f32x4*>(scsh + c0);
  f32x4 scb = *reinterpret_cast<const f32x4*>(scsh + c0 + 4);
  f32x4 sha = *reinterpret_cast<const f32x4*>(scsh + DD + c0);
  f32x4 shb = *reinterpret_cast<const f32x4*>(scsh + DD + c0 + 4);
  f32x8 acc = {};
  for (int rr = g; rr < 128; rr += 4) {
    const int row = blockIdx.x * 128 + rr;
    if (row < NN) {
      u16x8 rv = *reinterpret_cast<const u16x8*>(z + (size_t)row * DD + c0);
      f32x8 f = __builtin_convertvector(__builtin_bit_cast(bf16x8, rv), f32x8);
#pragma unroll
      for (int q = 0; q < 4; ++q) {
        acc[q]     += fmaxf(f[q]     * sca[q] + sha[q], 0.f);
        acc[q + 4] += fmaxf(f[q + 4] * scb[q] + shb[q], 0.f);
      }
    }
  }
#pragma unroll
  for (int q = 0; q < 8; ++q) red[g][c0 + q] = acc[q];
  __syncthreads();
  for (int cc = threadIdx.x; cc < DD; cc += 256) {
    const float s = red[0][cc] + red[1][cc] + red[2][cc] + red[3][cc];
    atomicAdd(&cs[cc], s);
  }
}

// ============ BN finalize (+ re-zero stats for next layer) ============
__global__ void bnfin_k(float* __restrict__ stats, const float* __restrict__ gamma,
                        const float* __restrict__ beta, float* __restrict__ scsh) {
  const int n = threadIdx.x;
  const float inv = 1.0f / (float)NN;
  const float mu = stats[n] * inv;
  const float var = stats[DD + n] * inv - mu * mu;
  const float sc = rsqrtf(var + 1e-5f) * gamma[n];
  scsh[n] = sc;
  scsh[DD + n] = beta[n] - mu * sc;
  stats[n] = 0.f;
  stats[DD + n] = 0.f;
}

// ============ fused GEMM: Z = bf16( X @ Wb^T + degp1 x cvec ), stats += colsum(z), colsum(z^2)
// 128x256 tile, 8 waves, 3-ring, counted vmcnt(6), 2-phase interleave, T2 swizzle.
__global__ __launch_bounds__(512, 2) void gemmf_k(
    const unsigned short* __restrict__ A, const unsigned short* __restrict__ B,
    unsigned short* __restrict__ Z, float* __restrict__ stats,
    const float* __restrict__ degp1, const float* __restrict__ cvec) {
  // memory order [A0][A2][A1][B0][B2][B1]; epilogue C (64KB @24576) covers B-ring0+ring2
  __shared__ unsigned short sm[73728];  // 144 KB
  constexpr int AOFF[3] = {0, 16384, 8192};
  constexpr int BOFF[3] = {24576, 57344, 40960};
  const int tid = threadIdx.x;
  const int lane = tid & 63;
  const int w = tid >> 6;
  const int rg = (w >> 2) * 64;
  const int cg = (w & 3) * 64;
  const int fr = lane & 15;
  const int fg = lane >> 4;
  const int sx = fr & 7;
  const int bid = blockIdx.x;
  const int swb = (bid & 7) * 98 + (bid >> 3);  // XCD-contiguous row bands (784 = 8*98)
  const int brow = (swb >> 1) * 128;
  const int bcol = (swb & 1) * 256;
  const char* Ab = (const char*)A + (size_t)brow * 1024;
  const char* Bb = (const char*)B + (size_t)bcol * 1024;
  const int srow = tid >> 3;
  const int sce = (tid & 7) * 8;                     // linear LDS dest (elems)
  const int sswz = (((tid & 7) ^ (srow & 7))) * 16;  // pre-swizzled global slot (bytes)

  f32x4 acc[4][4] = {};

  // prologue: stage tiles 0,1 (12 gloads in flight)
#pragma unroll
  for (int t = 0; t < 2; ++t) {
#pragma unroll
    for (int i = 0; i < 2; ++i)
      gload16(Ab + (size_t)(i * 64 + srow) * 1024 + t * 128 + sswz,
              &sm[AOFF[t] + (i * 64 + srow) * 64 + sce]);
#pragma unroll
    for (int i = 0; i < 4; ++i)
      gload16(Bb + (size_t)(i * 64 + srow) * 1024 + t * 128 + sswz,
              &sm[BOFF[t] + (i * 64 + srow) * 64 + sce]);
  }

#pragma unroll
  for (int kt = 0; kt < 8; ++kt) {
    if (kt < 7) asm volatile("s_waitcnt vmcnt(6)" ::: "memory");
    else        asm volatile("s_waitcnt vmcnt(0)" ::: "memory");
    __builtin_amdgcn_s_barrier();
    const unsigned short* la = &sm[AOFF[kt % 3]];
    const unsigned short* lb = &sm[BOFF[kt % 3]];
    bf16x8 av[4], bv[4];
    READ_FRAGS(la, lb, 0, av, bv);
    if (kt + 2 < 8) {
      const int t2 = kt + 2;
#pragma unroll
      for (int i = 0; i < 2; ++i)
        gload16(Ab + (size_t)(i * 64 + srow) * 1024 + t2 * 128 + sswz,
                &sm[AOFF[t2 % 3] + (i * 64 + srow) * 64 + sce]);
      gload16(Bb + (size_t)srow * 1024 + t2 * 128 + sswz,
              &sm[BOFF[t2 % 3] + srow * 64 + sce]);
    }
    PHASE_TAIL(av, bv)
    __builtin_amdgcn_s_barrier();
    READ_FRAGS(la, lb, 1, av, bv);
    if (kt + 2 < 8) {
      const int t2 = kt + 2;
#pragma unroll
      for (int i = 1; i < 4; ++i)
        gload16(Bb + (size_t)(i * 64 + srow) * 1024 + t2 * 128 + sswz,
                &sm[BOFF[t2 % 3] + (i * 64 + srow) * 64 + sce]);
    }
    PHASE_TAIL(av, bv)
  }

  // rank-1 correction: z += degp1(row) * cvec(col)  (pad rows: degp1==0)
  if (cvec != nullptr) {
    float cj[4];
#pragma unroll
    for (int j = 0; j < 4; ++j) cj[j] = cvec[bcol + cg + j * 16 + fr];
#pragma unroll
    for (int i = 0; i < 4; ++i)
#pragma unroll
      for (int r = 0; r < 4; ++r) {
        const float dgv = degp1[brow + rg + i * 16 + fg * 4 + r];
#pragma unroll
        for (int j = 0; j < 4; ++j) acc[i][j][r] += dgv * cj[j];
      }
  }

  // stats (from acc regs; pad rows contribute 0)
#pragma unroll
  for (int j = 0; j < 4; ++j) {
    const int col = bcol + cg + j * 16 + fr;
    float s1 = 0.f, s2 = 0.f;
#pragma unroll
    for (int i = 0; i < 4; ++i)
#pragma unroll
      for (int r = 0; r < 4; ++r) {
        const float v = acc[i][j][r];
        s1 += v;
        s2 += v * v;
      }
    s1 += __shfl_down(s1, 32);
    s2 += __shfl_down(s2, 32);
    s1 += __shfl_down(s1, 16);
    s2 += __shfl_down(s2, 16);
    if (lane < 16) {
      atomicAdd(&stats[col], s1);
      atomicAdd(&stats[DD + col], s2);
    }
  }

  // LDS-staged C write (swizzled: phys 16B-slot = logical ^ (row&7))
  unsigned short* C = &sm[24576];
#pragma unroll
  for (int j = 0; j < 4; ++j)
#pragma unroll
    for (int i = 0; i < 4; ++i)
#pragma unroll
      for (int r = 0; r < 4; ++r) {
        const int row = rg + i * 16 + fg * 4 + r;
        const int col = cg + j * 16 + fr;
        __bf16 b = (__bf16)acc[i][j][r];
        C[row * 256 + (((col >> 3) ^ (row & 7)) << 3) + (col & 7)] =
            __builtin_bit_cast(unsigned short, b);
      }
  asm volatile("s_waitcnt lgkmcnt(0)" ::: "memory");
  __builtin_amdgcn_s_barrier();
  const int orow = tid >> 2;
  const int ox = orow & 7;
  const unsigned short* cr = &C[orow * 256];
  unsigned short* zg = Z + (size_t)(brow + orow) * DD + bcol;
#pragma unroll
  for (int i = 0; i < 8; ++i) {
    const int s = (tid & 3) * 8 + ((i + tid) & 7);  // logical 16B slot 0..31
    *reinterpret_cast<u16x8*>(zg + s * 8) = *reinterpret_cast<const u16x8*>(cr + (s ^ ox) * 8);
  }
}

// ============ final outputs: out = colsum(act)@W2^T/NN + b2 ============
__global__ __launch_bounds__(512) void out_k(const float* __restrict__ cs3,
                                             const float* __restrict__ cs2,
                                             const float* __restrict__ W2all,
                                             const float* __restrict__ b2all,
                                             float* __restrict__ out) {
  __shared__ float s3[DD], s2[DD];
  s3[threadIdx.x] = cs3[threadIdx.x];
  s2[threadIdx.x] = cs2[threadIdx.x];
  __syncthreads();
  const int n = threadIdx.x;
  const float inv = 1.0f / (float)NN;
  const float* r3 = W2all + (size_t)3 * DD * DD + (size_t)n * DD;
  const float* r2 = W2all + (size_t)2 * DD * DD + (size_t)n * DD;
  float a = 0.f, b = 0.f;
  for (int k = 0; k < DD; k += 4) {
    f32x4 v3 = *reinterpret_cast<const f32x4*>(r3 + k);
    f32x4 v2 = *reinterpret_cast<const f32x4*>(r2 + k);
    a += v3[0] * s3[k] + v3[1] * s3[k + 1] + v3[2] * s3[k + 2] + v3[3] * s3[k + 3];
    b += v2[0] * s2[k] + v2[1] * s2[k + 1] + v2[2] * s2[k + 2] + v2[3] * s2[k + 3];
  }
  out[n]      = a * inv + b2all[3 * DD + n];  // outs[-1] = layer 3
  out[DD + n] = b * inv + b2all[2 * DD + n];  // outs[-2] = layer 2
}

extern "C" void kernel_launch(void* const* d_in, const int* in_sizes, int n_in,
                              void* d_out, int out_size, void* d_ws, size_t ws_size,
                              hipStream_t stream) {
  const float* x     = (const float*)d_in[0];
  const float* W1    = (const float*)d_in[1];
  // d_in[2] = b1: cancels exactly in training-mode BatchNorm -> unused
  const float* gamma = (const float*)d_in[3];
  const float* beta  = (const float*)d_in[4];
  const float* W2    = (const float*)d_in[5];
  const float* b2    = (const float*)d_in[6];
  const int*   src   = (const int*)d_in[7];
  const int*   dst   = (const int*)d_in[8];
  float* out = (float*)d_out;

  char* ws = (char*)d_ws;
  const size_t ABYTES = (size_t)MPAD * DD * 2;  // 51,380,224
  unsigned short* xact   = (unsigned short*)(ws);
  unsigned short* z      = (unsigned short*)(ws + ABYTES);
  unsigned short* wb1    = (unsigned short*)(ws + 2 * ABYTES);               // 512KB
  unsigned short* wf     = (unsigned short*)(ws + 2 * ABYTES + 524288);      // 3x512KB
  float*          w2t    = (float*)(ws + 2 * ABYTES + 2097152);              // 3x1MB
  float*          cvec   = (float*)(ws + 2 * ABYTES + 5242880);              // 6KB
  float*          cs2    = (float*)(ws + 2 * ABYTES + 5251072);
  float*          cs3    = (float*)(ws + 2 * ABYTES + 5255168);
  float*          stats  = (float*)(ws + 2 * ABYTES + 5259264);
  float*          scsh   = (float*)(ws + 2 * ABYTES + 5263360);
  float*          degp1  = (float*)(ws + 2 * ABYTES + 5267456);              // MPAD*4
  int*            rowptr = (int*)(ws + 2 * ABYTES + 5468160);
  int*            cursor = (int*)(ws + 2 * ABYTES + 5668864);
  int*            csrc   = (int*)(ws + 2 * ABYTES + 5869568);

  // --- weight prep (once per call) ---
  wconv0_k<<<128, 256, 0, stream>>>(W1, wb1);
  trans_k<<<dim3(8, 8, 3), 256, 0, stream>>>(W2, w2t);
  wfuse_k<<<dim3(4, 4, 3), 256, 0, stream>>>(W1, w2t, wf);
  cvec_k<<<3, 512, 0, stream>>>(W1, b2, cvec);

  // zero xact pad rows once (agg kernels never write them; zeros keep stats/colsum exact)
  hipMemsetAsync(xact + (size_t)NN * DD, 0, (size_t)(MPAD - NN) * DD * 2, stream);
  hipMemsetAsync(cs2, 0, DD * sizeof(float), stream);
  hipMemsetAsync(cs3, 0, DD * sizeof(float), stream);
  hipMemsetAsync(stats, 0, 2 * DD * sizeof(float), stream);

  // --- CSR build (once) ---
  hipMemsetAsync(cursor, 0, NN * sizeof(int), stream);
  count_k<<<(NE + 255) / 256, 256, 0, stream>>>(dst, cursor);
  scan_k<<<1, 1024, 0, stream>>>(cursor, rowptr, cursor);
  fill_k<<<(NE + 255) / 256, 256, 0, stream>>>(src, dst, cursor, csrc);
  degp1_k<<<(MPAD + 255) / 256, 256, 0, stream>>>(rowptr, degp1);

  // --- layer 0: z0 = (x + agg x) @ W1_0^T ---
  agg_f32_k<<<NN / 4, 256, 0, stream>>>(x, rowptr, csrc, xact);
  gemmf_k<<<784, 512, 0, stream>>>(xact, wb1, z, stats, degp1, nullptr);
  bnfin_k<<<1, DD, 0, stream>>>(stats, gamma, beta, scsh);

  // --- boundaries l -> l+1 (fused W1_{l+1} @ W2_l) ---
  for (int l = 0; l < 3; ++l) {
    agg_act_k<<<NN / 4, 256, 0, stream>>>(z, scsh, rowptr, csrc, xact);
    if (l == 2) colsum_act_k<<<392, 256, 0, stream>>>(z, scsh, cs2);  // colsum(act_2)
    gemmf_k<<<784, 512, 0, stream>>>(xact, wf + (size_t)l * DD * DD, z, stats,
                                     degp1, cvec + l * DD);
    bnfin_k<<<1, DD, 0, stream>>>(stats, gamma + (l + 1) * DD, beta + (l + 1) * DD, scsh);
  }

  colsum_act_k<<<392, 256, 0, stream>>>(z, scsh, cs3);  // colsum(act_3)
  out_k<<<1, 512, 0, stream>>>(cs3, cs2, W2, b2, out);
}